// Round 1
// 736.588 us; speedup vs baseline: 1.0348x; 1.0348x over previous
//
#include <hip/hip_runtime.h>
#include <hip/hip_bf16.h>

typedef __bf16 bf16;
typedef __attribute__((ext_vector_type(8))) __bf16 bf16x8;
typedef __attribute__((ext_vector_type(4))) __bf16 bf16x4;
typedef __attribute__((ext_vector_type(4))) float f32x4;

#define MFMA16(a, b, c) __builtin_amdgcn_mfma_f32_16x16x32_bf16((a), (b), (c), 0, 0, 0)

__device__ __forceinline__ void gld_lds16(const bf16* g, bf16* l) {
    __builtin_amdgcn_global_load_lds(
        (const __attribute__((address_space(1))) void*)g,
        (__attribute__((address_space(3))) void*)l, 16, 0, 0);
}

// ---------------------------------------------------------------------------
// Kernel 1: weight transpose + f32->bf16 cast.  W [1024(k)][1024(n)] f32 ->
// Wt [1024(n)][1024(k)] bf16.
// ---------------------------------------------------------------------------
__global__ __launch_bounds__(256) void wcvt_kernel(
    const float* __restrict__ W0, const float* __restrict__ W1,
    const float* __restrict__ W2, const float* __restrict__ W3,
    bf16* __restrict__ T0, bf16* __restrict__ T1,
    bf16* __restrict__ T2, bf16* __restrict__ T3)
{
    const int z = blockIdx.z;
    const float* W = (z == 0) ? W0 : (z == 1) ? W1 : (z == 2) ? W2 : W3;
    bf16* T = (z == 0) ? T0 : (z == 1) ? T1 : (z == 2) ? T2 : T3;
    const int k0 = blockIdx.x * 64, n0 = blockIdx.y * 64;
    const int tid = threadIdx.x;

    __shared__ float tile[64][65];

    #pragma unroll
    for (int rr = 0; rr < 4; ++rr) {
        int r = (tid >> 4) + rr * 16;
        int cg = (tid & 15) * 4;
        float4 v = *(const float4*)(W + (size_t)(k0 + r) * 1024 + n0 + cg);
        tile[r][cg + 0] = v.x; tile[r][cg + 1] = v.y;
        tile[r][cg + 2] = v.z; tile[r][cg + 3] = v.w;
    }
    __syncthreads();

    const int n_local = tid >> 2;
    const int kg = (tid & 3) * 16;
    bf16x8 v0, v1;
    #pragma unroll
    for (int j = 0; j < 8; ++j) v0[j] = (bf16)tile[kg + j][n_local];
    #pragma unroll
    for (int j = 0; j < 8; ++j) v1[j] = (bf16)tile[kg + 8 + j][n_local];
    bf16* dst = T + (size_t)(n0 + n_local) * 1024 + k0 + kg;
    *(bf16x8*)dst = v0;
    *(bf16x8*)(dst + 8) = v1;
}

// ---------------------------------------------------------------------------
// Kernel 2: X f32 -> bf16 cast (enables global_load_lds staging in the GEMM).
// ---------------------------------------------------------------------------
__global__ __launch_bounds__(256) void xcast_kernel(
    const float* __restrict__ Xq, const float* __restrict__ Xk, const float* __restrict__ Xv,
    bf16* __restrict__ Yq, bf16* __restrict__ Yk, bf16* __restrict__ Yv)
{
    const int z = blockIdx.z;
    const float* X = (z == 0) ? Xq : (z == 1) ? Xk : Xv;
    bf16* Y = (z == 0) ? Yq : (z == 1) ? Yk : Yv;
    const size_t i = ((size_t)blockIdx.x * 256 + threadIdx.x) * 8;
    float4 a = *(const float4*)(X + i);
    float4 b = *(const float4*)(X + i + 4);
    bf16x8 o = {(bf16)a.x, (bf16)a.y, (bf16)a.z, (bf16)a.w,
                (bf16)b.x, (bf16)b.y, (bf16)b.z, (bf16)b.w};
    *(bf16x8*)(Y + i) = o;
}

// ---------------------------------------------------------------------------
// Kernel 3: QKV projection, m97-style. 128x128 tile, 4 waves (each 64x64),
// LDS staging via global_load_lds width=16, K-step 32.
// A = Xbf [4096][1024] bf16 row-major; B = Wt [1024 n][1024 k] bf16.
// Epilogue scatters: Q,K -> [b][h][s][64]; V -> [b][h][64][s] (transposed).
// ---------------------------------------------------------------------------
__global__ __launch_bounds__(256) void qkv_gemm(
    const bf16* __restrict__ Xq, const bf16* __restrict__ Xk, const bf16* __restrict__ Xv,
    const bf16* __restrict__ Wtq, const bf16* __restrict__ Wtk, const bf16* __restrict__ Wtv,
    bf16* __restrict__ Qb, bf16* __restrict__ Kb, bf16* __restrict__ VT)
{
    const int z = blockIdx.z;
    const bf16* X = (z == 0) ? Xq : (z == 1) ? Xk : Xv;
    const bf16* Wt = (z == 0) ? Wtq : (z == 1) ? Wtk : Wtv;
    const int n0 = blockIdx.x * 128;
    const int m0 = blockIdx.y * 128;
    const int tid = threadIdx.x, w = tid >> 6, lane = tid & 63;
    const int quad = lane >> 4, c = lane & 15;
    const int wm = w & 1, wn = w >> 1;

    __shared__ bf16 As[128 * 32];
    __shared__ bf16 Bs[128 * 32];

    f32x4 acc[4][4];
    #pragma unroll
    for (int mt = 0; mt < 4; ++mt)
        #pragma unroll
        for (int nt = 0; nt < 4; ++nt) acc[mt][nt] = (f32x4){0.f, 0.f, 0.f, 0.f};

    const int lrow = lane >> 2;        // 0..15
    const int lk = (lane & 3) * 8;     // 0,8,16,24

    for (int k0 = 0; k0 < 1024; k0 += 32) {
        #pragma unroll
        for (int half = 0; half < 2; ++half) {
            const int row = half * 64 + w * 16 + lrow;
            gld_lds16(X + (size_t)(m0 + row) * 1024 + k0 + lk, As + row * 32 + lk);
            gld_lds16(Wt + (size_t)(n0 + row) * 1024 + k0 + lk, Bs + row * 32 + lk);
        }
        __syncthreads();
        bf16x8 af[4], bv[4];
        #pragma unroll
        for (int mt = 0; mt < 4; ++mt)
            af[mt] = *(const bf16x8*)&As[(wm * 64 + mt * 16 + c) * 32 + quad * 8];
        #pragma unroll
        for (int nt = 0; nt < 4; ++nt)
            bv[nt] = *(const bf16x8*)&Bs[(wn * 64 + nt * 16 + c) * 32 + quad * 8];
        #pragma unroll
        for (int mt = 0; mt < 4; ++mt)
            #pragma unroll
            for (int nt = 0; nt < 4; ++nt)
                acc[mt][nt] = MFMA16(af[mt], bv[nt], acc[mt][nt]);
        __syncthreads();
    }

    #pragma unroll
    for (int mt = 0; mt < 4; ++mt) {
        const int mb = m0 + wm * 64 + mt * 16 + quad * 4;
        const int b = mb >> 10, s = mb & 1023;
        #pragma unroll
        for (int nt = 0; nt < 4; ++nt) {
            const int n = n0 + wn * 64 + nt * 16 + c;
            const int h = n >> 6, d = n & 63;
            if (z == 2) {
                bf16x4 v = {(bf16)acc[mt][nt][0], (bf16)acc[mt][nt][1],
                            (bf16)acc[mt][nt][2], (bf16)acc[mt][nt][3]};
                *(bf16x4*)(VT + ((size_t)(b * 16 + h) * 64 + d) * 1024 + s) = v;
            } else {
                bf16* dst = ((z == 0) ? Qb : Kb) + ((size_t)(b * 16 + h) * 1024 + s) * 64 + d;
                #pragma unroll
                for (int i = 0; i < 4; ++i) dst[(size_t)i * 64] = (bf16)acc[mt][nt][i];
            }
        }
    }
}

// ---------------------------------------------------------------------------
// Kernel 4: attention, 8 waves/block (512 thr). Wave w: q-subtile (w&3, 16
// rows) x key-half (w>>2, 512 keys). Doubles resident waves vs the 4-wave
// version (grid 1024 blocks x 4 waves capped occupancy at 50%; latency-bound
// loop showed MfmaUtil 3.7 / VALUBusy 14.7 / Occ 46%).
// Pass-1 partial row-sums combine via LDS; pass-2 attn writes are disjoint
// per wave; partial ctx^T combines via LDS at the end.
// ---------------------------------------------------------------------------
__global__ __launch_bounds__(512) void attn_kernel(
    const bf16* __restrict__ Qb, const bf16* __restrict__ Kb, const bf16* __restrict__ VT,
    const float* __restrict__ lps, const unsigned char* __restrict__ mask,
    const float* __restrict__ cwp, const float* __restrict__ cbp,
    float* __restrict__ attn, bf16* __restrict__ ctxb)
{
    const int qt = blockIdx.x, h = blockIdx.y, b = blockIdx.z;
    const int tid = threadIdx.x, w = tid >> 6, lane = tid & 63;
    const int qsub = w & 3, shalf = w >> 2;
    const int quad = lane >> 4, c = lane & 15;
    const float cw = cwp[0], cb = cbp[0];
    const int q0 = qt * 64 + qsub * 16;
    const int sbeg = shalf * 512;
    const size_t bh = (size_t)(b * 16 + h);

    const bf16* qptr = Qb + (bh * 1024 + q0 + c) * 64;
    const bf16x8 qf0 = *(const bf16x8*)(qptr + quad * 8);
    const bf16x8 qf1 = *(const bf16x8*)(qptr + 32 + quad * 8);
    const bf16* kbase = Kb + bh * 1024 * 64;
    const bf16* vbase = VT + bh * 64 * 1024;
    const unsigned char* mbase = mask + (size_t)b * 1024 * 1024;
    const float* lbase = lps + (size_t)(q0 + c) * 1024;
    const unsigned char* mrow = mbase + (size_t)(q0 + c) * 1024;

    __shared__ float ssum[2][4][16];
    __shared__ f32x4 cbuf[4][4][64];

    // ---- pass 1: partial row sum of exp(score) over this wave's key-half ----
    float sum = 0.f;
    #pragma unroll 2
    for (int s0 = sbeg; s0 < sbeg + 512; s0 += 16) {
        const bf16* kr = kbase + (size_t)(s0 + c) * 64;
        bf16x8 kf0 = *(const bf16x8*)(kr + quad * 8);
        bf16x8 kf1 = *(const bf16x8*)(kr + 32 + quad * 8);
        f32x4 sacc = {0.f, 0.f, 0.f, 0.f};
        sacc = MFMA16(kf0, qf0, sacc);   // S^T: row = s, col = q
        sacc = MFMA16(kf1, qf1, sacc);
        float4 lp = *(const float4*)(lbase + s0 + quad * 4);
        unsigned int mw = *(const unsigned int*)(mrow + s0 + quad * 4);
        #pragma unroll
        for (int i = 0; i < 4; ++i) {
            float sc = sacc[i] * 0.125f + cw * ((const float*)&lp)[i] + cb;
            if ((mw >> (8 * i)) & 0xff) sc = -1e9f;
            sum += __expf(sc);
        }
    }
    sum += __shfl_xor(sum, 16);
    sum += __shfl_xor(sum, 32);
    if (lane < 16) ssum[shalf][qsub][lane] = sum;
    __syncthreads();
    const float rl = 1.0f / (ssum[0][qsub][c] + ssum[1][qsub][c]);

    // ---- pass 2: write normalized attn + partial PV over this key-half ----
    f32x4 ctxT[4];
    #pragma unroll
    for (int dt = 0; dt < 4; ++dt) ctxT[dt] = (f32x4){0.f, 0.f, 0.f, 0.f};
    float* abase = attn + bh * 1024 * 1024 + (size_t)(q0 + c) * 1024;

    #pragma unroll 2
    for (int s0 = sbeg; s0 < sbeg + 512; s0 += 16) {
        const bf16* kr = kbase + (size_t)(s0 + c) * 64;
        bf16x8 kf0 = *(const bf16x8*)(kr + quad * 8);
        bf16x8 kf1 = *(const bf16x8*)(kr + 32 + quad * 8);
        f32x4 sacc = {0.f, 0.f, 0.f, 0.f};
        sacc = MFMA16(kf0, qf0, sacc);
        sacc = MFMA16(kf1, qf1, sacc);
        float4 lp = *(const float4*)(lbase + s0 + quad * 4);
        unsigned int mw = *(const unsigned int*)(mrow + s0 + quad * 4);
        float e[4];
        #pragma unroll
        for (int i = 0; i < 4; ++i) {
            float sc = sacc[i] * 0.125f + cw * ((const float*)&lp)[i] + cb;
            if ((mw >> (8 * i)) & 0xff) sc = -1e9f;
            e[i] = __expf(sc);
        }
        f32x4 st = {e[0] * rl, e[1] * rl, e[2] * rl, e[3] * rl};
        *(f32x4*)(abase + s0 + quad * 4) = st;
        // B-operand: k = quad*8 + j; j<4 -> s = s0 + quad*4 + j, j>=4 -> zero
        bf16x8 pf = {(bf16)e[0], (bf16)e[1], (bf16)e[2], (bf16)e[3],
                     (bf16)0.f, (bf16)0.f, (bf16)0.f, (bf16)0.f};
        #pragma unroll
        for (int dt = 0; dt < 4; ++dt) {
            bf16x4 vv = *(const bf16x4*)(vbase + (size_t)(dt * 16 + c) * 1024 + s0 + quad * 4);
            bf16x8 af = {vv[0], vv[1], vv[2], vv[3],
                         (bf16)0.f, (bf16)0.f, (bf16)0.f, (bf16)0.f};
            ctxT[dt] = MFMA16(af, pf, ctxT[dt]);   // ctx^T: row = d, col = q
        }
    }

    // ---- combine ctx^T partials across the two key-halves, write ctx ----
    if (shalf == 1) {
        #pragma unroll
        for (int dt = 0; dt < 4; ++dt) cbuf[qsub][dt][lane] = ctxT[dt];
    }
    __syncthreads();
    if (shalf == 0) {
        #pragma unroll
        for (int dt = 0; dt < 4; ++dt) {
            f32x4 t = cbuf[qsub][dt][lane];
            bf16x4 v = {(bf16)((ctxT[dt][0] + t[0]) * rl), (bf16)((ctxT[dt][1] + t[1]) * rl),
                        (bf16)((ctxT[dt][2] + t[2]) * rl), (bf16)((ctxT[dt][3] + t[3]) * rl)};
            *(bf16x4*)(ctxb + ((size_t)b * 1024 + q0 + c) * 1024 + h * 64 + dt * 16 + quad * 4) = v;
        }
    }
}

// ---------------------------------------------------------------------------
// Kernel 5: out_pre = ctx @ W_fc + input_Q, same m97 GEMM structure.
// ---------------------------------------------------------------------------
__global__ __launch_bounds__(256) void fc_gemm(
    const bf16* __restrict__ ctxb, const bf16* __restrict__ Wt,
    const float* __restrict__ resid, float* __restrict__ outp)
{
    const int n0 = blockIdx.x * 128;
    const int m0 = blockIdx.y * 128;
    const int tid = threadIdx.x, w = tid >> 6, lane = tid & 63;
    const int quad = lane >> 4, c = lane & 15;
    const int wm = w & 1, wn = w >> 1;

    __shared__ bf16 As[128 * 32];
    __shared__ bf16 Bs[128 * 32];

    f32x4 acc[4][4];
    #pragma unroll
    for (int mt = 0; mt < 4; ++mt)
        #pragma unroll
        for (int nt = 0; nt < 4; ++nt) acc[mt][nt] = (f32x4){0.f, 0.f, 0.f, 0.f};

    const int lrow = lane >> 2;
    const int lk = (lane & 3) * 8;

    for (int k0 = 0; k0 < 1024; k0 += 32) {
        #pragma unroll
        for (int half = 0; half < 2; ++half) {
            const int row = half * 64 + w * 16 + lrow;
            gld_lds16(ctxb + (size_t)(m0 + row) * 1024 + k0 + lk, As + row * 32 + lk);
            gld_lds16(Wt + (size_t)(n0 + row) * 1024 + k0 + lk, Bs + row * 32 + lk);
        }
        __syncthreads();
        bf16x8 af[4], bv[4];
        #pragma unroll
        for (int mt = 0; mt < 4; ++mt)
            af[mt] = *(const bf16x8*)&As[(wm * 64 + mt * 16 + c) * 32 + quad * 8];
        #pragma unroll
        for (int nt = 0; nt < 4; ++nt)
            bv[nt] = *(const bf16x8*)&Bs[(wn * 64 + nt * 16 + c) * 32 + quad * 8];
        #pragma unroll
        for (int mt = 0; mt < 4; ++mt)
            #pragma unroll
            for (int nt = 0; nt < 4; ++nt)
                acc[mt][nt] = MFMA16(af[mt], bv[nt], acc[mt][nt]);
        __syncthreads();
    }

    #pragma unroll
    for (int mt = 0; mt < 4; ++mt) {
        const int mb = m0 + wm * 64 + mt * 16 + quad * 4;
        #pragma unroll
        for (int nt = 0; nt < 4; ++nt) {
            const int n = n0 + wn * 64 + nt * 16 + c;
            #pragma unroll
            for (int i = 0; i < 4; ++i) {
                const size_t idx = (size_t)(mb + i) * 1024 + n;
                outp[idx] = acc[mt][nt][i] + resid[idx];
            }
        }
    }
}

// ---------------------------------------------------------------------------
// Kernel 6: LayerNorm over last dim (1024).
// ---------------------------------------------------------------------------
__global__ __launch_bounds__(256) void ln_kernel(
    const float* __restrict__ xp, float* __restrict__ out)
{
    const int row = blockIdx.x, tid = threadIdx.x;
    const float* p = xp + (size_t)row * 1024 + tid * 4;
    float4 x = *(const float4*)p;
    float s = x.x + x.y + x.z + x.w;
    float q = x.x * x.x + x.y * x.y + x.z * x.z + x.w * x.w;
    #pragma unroll
    for (int off = 32; off >= 1; off >>= 1) {
        s += __shfl_down(s, off);
        q += __shfl_down(q, off);
    }
    __shared__ float sb[4], qb[4];
    const int w = tid >> 6, lane = tid & 63;
    if (lane == 0) { sb[w] = s; qb[w] = q; }
    __syncthreads();
    const float ts = sb[0] + sb[1] + sb[2] + sb[3];
    const float tq = qb[0] + qb[1] + qb[2] + qb[3];
    const float mean = ts * (1.0f / 1024.0f);
    const float var = tq * (1.0f / 1024.0f) - mean * mean;
    const float rs = rsqrtf(var + 1e-5f);
    float4 o;
    o.x = (x.x - mean) * rs; o.y = (x.y - mean) * rs;
    o.z = (x.z - mean) * rs; o.w = (x.w - mean) * rs;
    *(float4*)(out + (size_t)row * 1024 + tid * 4) = o;
}

// ---------------------------------------------------------------------------
extern "C" void kernel_launch(void* const* d_in, const int* in_sizes, int n_in,
                              void* d_out, int out_size, void* d_ws, size_t ws_size,
                              hipStream_t stream)
{
    const float* Xq  = (const float*)d_in[0];
    const float* Xk  = (const float*)d_in[1];
    const float* Xv  = (const float*)d_in[2];
    const unsigned char* mask = (const unsigned char*)d_in[3];
    const float* lps = (const float*)d_in[4];
    const float* Wq  = (const float*)d_in[5];
    const float* Wk  = (const float*)d_in[6];
    const float* Wv  = (const float*)d_in[7];
    const float* Wfc = (const float*)d_in[8];
    const float* cw  = (const float*)d_in[9];
    const float* cb  = (const float*)d_in[10];

    char* ws = (char*)d_ws;
    const size_t MB = 1024 * 1024;
    bf16* Wtq = (bf16*)(ws + 0 * MB);
    bf16* Wtk = (bf16*)(ws + 2 * MB);
    bf16* Wtv = (bf16*)(ws + 4 * MB);
    bf16* Wtf = (bf16*)(ws + 6 * MB);
    bf16* Qb  = (bf16*)(ws + 8 * MB);      // [4][16][1024][64]
    bf16* Kb  = (bf16*)(ws + 16 * MB);     // [4][16][1024][64]
    bf16* VT  = (bf16*)(ws + 24 * MB);     // [4][16][64][1024]
    // Xbf lifetime: [xcast, qkv_gemm]; ctx written by attn (later), outp by fc
    bf16* Xbq = (bf16*)(ws + 32 * MB);     // overlaps ctx region
    bf16* Xbk = (bf16*)(ws + 40 * MB);     // overlaps outp region
    bf16* Xbv = (bf16*)(ws + 48 * MB);     // overlaps outp region
    bf16* ctx = (bf16*)(ws + 32 * MB);     // [4096][1024] bf16
    float* outp = (float*)(ws + 40 * MB);  // [4096][1024] f32

    float* out_ln = (float*)d_out;
    float* attn   = (float*)d_out + (size_t)4 * MB;

    wcvt_kernel<<<dim3(16, 16, 4), 256, 0, stream>>>(Wq, Wk, Wv, Wfc, Wtq, Wtk, Wtv, Wtf);
    xcast_kernel<<<dim3(2048, 1, 3), 256, 0, stream>>>(Xq, Xk, Xv, Xbq, Xbk, Xbv);
    qkv_gemm<<<dim3(8, 32, 3), 256, 0, stream>>>(Xbq, Xbk, Xbv, Wtq, Wtk, Wtv, Qb, Kb, VT);
    attn_kernel<<<dim3(16, 16, 4), 512, 0, stream>>>(Qb, Kb, VT, lps, mask, cw, cb, attn, ctx);
    fc_gemm<<<dim3(8, 32, 1), 256, 0, stream>>>(ctx, Wtf, Xq, outp);
    ln_kernel<<<4096, 256, 0, stream>>>(outp, out_ln);
}

// Round 2
// 678.762 us; speedup vs baseline: 1.1230x; 1.0852x over previous
//
#include <hip/hip_runtime.h>
#include <hip/hip_bf16.h>

typedef __bf16 bf16;
typedef __attribute__((ext_vector_type(8))) __bf16 bf16x8;
typedef __attribute__((ext_vector_type(4))) __bf16 bf16x4;
typedef __attribute__((ext_vector_type(4))) float f32x4;

#define MFMA16(a, b, c) __builtin_amdgcn_mfma_f32_16x16x32_bf16((a), (b), (c), 0, 0, 0)

__device__ __forceinline__ void gld_lds16(const bf16* g, bf16* l) {
    __builtin_amdgcn_global_load_lds(
        (const __attribute__((address_space(1))) void*)g,
        (__attribute__((address_space(3))) void*)l, 16, 0, 0);
}

// ---------------------------------------------------------------------------
// Kernel 1: weight transpose + f32->bf16 cast.  W [1024(k)][1024(n)] f32 ->
// Wt [1024(n)][1024(k)] bf16.
// ---------------------------------------------------------------------------
__global__ __launch_bounds__(256) void wcvt_kernel(
    const float* __restrict__ W0, const float* __restrict__ W1,
    const float* __restrict__ W2, const float* __restrict__ W3,
    bf16* __restrict__ T0, bf16* __restrict__ T1,
    bf16* __restrict__ T2, bf16* __restrict__ T3)
{
    const int z = blockIdx.z;
    const float* W = (z == 0) ? W0 : (z == 1) ? W1 : (z == 2) ? W2 : W3;
    bf16* T = (z == 0) ? T0 : (z == 1) ? T1 : (z == 2) ? T2 : T3;
    const int k0 = blockIdx.x * 64, n0 = blockIdx.y * 64;
    const int tid = threadIdx.x;

    __shared__ float tile[64][65];

    #pragma unroll
    for (int rr = 0; rr < 4; ++rr) {
        int r = (tid >> 4) + rr * 16;
        int cg = (tid & 15) * 4;
        float4 v = *(const float4*)(W + (size_t)(k0 + r) * 1024 + n0 + cg);
        tile[r][cg + 0] = v.x; tile[r][cg + 1] = v.y;
        tile[r][cg + 2] = v.z; tile[r][cg + 3] = v.w;
    }
    __syncthreads();

    const int n_local = tid >> 2;
    const int kg = (tid & 3) * 16;
    bf16x8 v0, v1;
    #pragma unroll
    for (int j = 0; j < 8; ++j) v0[j] = (bf16)tile[kg + j][n_local];
    #pragma unroll
    for (int j = 0; j < 8; ++j) v1[j] = (bf16)tile[kg + 8 + j][n_local];
    bf16* dst = T + (size_t)(n0 + n_local) * 1024 + k0 + kg;
    *(bf16x8*)dst = v0;
    *(bf16x8*)(dst + 8) = v1;
}

// ---------------------------------------------------------------------------
// Kernel 2: X f32 -> bf16 cast (enables global_load_lds staging in the GEMM).
// ---------------------------------------------------------------------------
__global__ __launch_bounds__(256) void xcast_kernel(
    const float* __restrict__ Xq, const float* __restrict__ Xk, const float* __restrict__ Xv,
    bf16* __restrict__ Yq, bf16* __restrict__ Yk, bf16* __restrict__ Yv)
{
    const int z = blockIdx.z;
    const float* X = (z == 0) ? Xq : (z == 1) ? Xk : Xv;
    bf16* Y = (z == 0) ? Yq : (z == 1) ? Yk : Yv;
    const size_t i = ((size_t)blockIdx.x * 256 + threadIdx.x) * 8;
    float4 a = *(const float4*)(X + i);
    float4 b = *(const float4*)(X + i + 4);
    bf16x8 o = {(bf16)a.x, (bf16)a.y, (bf16)a.z, (bf16)a.w,
                (bf16)b.x, (bf16)b.y, (bf16)b.z, (bf16)b.w};
    *(bf16x8*)(Y + i) = o;
}

// ---------------------------------------------------------------------------
// Kernel 3: QKV projection, m97-style. 128x128 tile, 4 waves (each 64x64),
// LDS staging via global_load_lds width=16, K-step 32.
// ---------------------------------------------------------------------------
__global__ __launch_bounds__(256) void qkv_gemm(
    const bf16* __restrict__ Xq, const bf16* __restrict__ Xk, const bf16* __restrict__ Xv,
    const bf16* __restrict__ Wtq, const bf16* __restrict__ Wtk, const bf16* __restrict__ Wtv,
    bf16* __restrict__ Qb, bf16* __restrict__ Kb, bf16* __restrict__ VT)
{
    const int z = blockIdx.z;
    const bf16* X = (z == 0) ? Xq : (z == 1) ? Xk : Xv;
    const bf16* Wt = (z == 0) ? Wtq : (z == 1) ? Wtk : Wtv;
    const int n0 = blockIdx.x * 128;
    const int m0 = blockIdx.y * 128;
    const int tid = threadIdx.x, w = tid >> 6, lane = tid & 63;
    const int quad = lane >> 4, c = lane & 15;
    const int wm = w & 1, wn = w >> 1;

    __shared__ bf16 As[128 * 32];
    __shared__ bf16 Bs[128 * 32];

    f32x4 acc[4][4];
    #pragma unroll
    for (int mt = 0; mt < 4; ++mt)
        #pragma unroll
        for (int nt = 0; nt < 4; ++nt) acc[mt][nt] = (f32x4){0.f, 0.f, 0.f, 0.f};

    const int lrow = lane >> 2;        // 0..15
    const int lk = (lane & 3) * 8;     // 0,8,16,24

    for (int k0 = 0; k0 < 1024; k0 += 32) {
        #pragma unroll
        for (int half = 0; half < 2; ++half) {
            const int row = half * 64 + w * 16 + lrow;
            gld_lds16(X + (size_t)(m0 + row) * 1024 + k0 + lk, As + row * 32 + lk);
            gld_lds16(Wt + (size_t)(n0 + row) * 1024 + k0 + lk, Bs + row * 32 + lk);
        }
        __syncthreads();
        bf16x8 af[4], bv[4];
        #pragma unroll
        for (int mt = 0; mt < 4; ++mt)
            af[mt] = *(const bf16x8*)&As[(wm * 64 + mt * 16 + c) * 32 + quad * 8];
        #pragma unroll
        for (int nt = 0; nt < 4; ++nt)
            bv[nt] = *(const bf16x8*)&Bs[(wn * 64 + nt * 16 + c) * 32 + quad * 8];
        #pragma unroll
        for (int mt = 0; mt < 4; ++mt)
            #pragma unroll
            for (int nt = 0; nt < 4; ++nt)
                acc[mt][nt] = MFMA16(af[mt], bv[nt], acc[mt][nt]);
        __syncthreads();
    }

    #pragma unroll
    for (int mt = 0; mt < 4; ++mt) {
        const int mb = m0 + wm * 64 + mt * 16 + quad * 4;
        const int b = mb >> 10, s = mb & 1023;
        #pragma unroll
        for (int nt = 0; nt < 4; ++nt) {
            const int n = n0 + wn * 64 + nt * 16 + c;
            const int h = n >> 6, d = n & 63;
            if (z == 2) {
                bf16x4 v = {(bf16)acc[mt][nt][0], (bf16)acc[mt][nt][1],
                            (bf16)acc[mt][nt][2], (bf16)acc[mt][nt][3]};
                *(bf16x4*)(VT + ((size_t)(b * 16 + h) * 64 + d) * 1024 + s) = v;
            } else {
                bf16* dst = ((z == 0) ? Qb : Kb) + ((size_t)(b * 16 + h) * 1024 + s) * 64 + d;
                #pragma unroll
                for (int i = 0; i < 4; ++i) dst[(size_t)i * 64] = (bf16)acc[mt][nt][i];
            }
        }
    }
}

// ---------------------------------------------------------------------------
// Kernel 4: flash-style attention, fully coalesced global access.
// Per block: 64 q-rows x all 1024 keys, 4 waves as 2(q-half) x 2(s/d-half).
// S computed NON-transposed (A=Q, B=K from LDS) so D-layout col = s = lane&15:
// lps/mask reads and the 256MB attn f32 store are lane-contiguous.
// K and V^T staged via global_load_lds (linear dests); P bounced to PV's
// A-operand through a padded LDS tile ([64][40] bf16, low bank conflict).
// Sweep 1 accumulates row sums (shfl + 512B LDS reduce); sweep 2 recomputes
// scores, writes normalized attn, and accumulates PV into registers.
// Rationale: previous version read K/V/lps/mask/attn directly in MFMA
// fragment lane order (consecutive lanes 128B-4KB apart) -> zero coalescing,
// TA/L1 segment throughput saturated (dur flat when waves doubled, all
// counted pipes <16%).
// ---------------------------------------------------------------------------
__global__ __launch_bounds__(256) void attn_kernel(
    const bf16* __restrict__ Qb, const bf16* __restrict__ Kb, const bf16* __restrict__ VT,
    const float* __restrict__ lps, const unsigned char* __restrict__ mask,
    const float* __restrict__ cwp, const float* __restrict__ cbp,
    float* __restrict__ attn, bf16* __restrict__ ctxb)
{
    const int qt = blockIdx.x, h = blockIdx.y, b = blockIdx.z;
    const int tid = threadIdx.x, w = tid >> 6, lane = tid & 63;
    const int quad = lane >> 4, c = lane & 15;
    const int wq = w & 1, ws = w >> 1;
    const float cw = cwp[0], cbv = cbp[0];
    const int m0 = qt * 64;
    const size_t bh = (size_t)(b * 16 + h);

    const bf16* qbase = Qb + bh * 1024 * 64;
    const bf16* kbase = Kb + bh * 1024 * 64;
    const bf16* vbase = VT + bh * 64 * 1024;
    const unsigned char* mbase = mask + (size_t)b * 1024 * 1024;
    float* abase = attn + bh * 1024 * 1024;

    __shared__ bf16 Ks[2][64 * 32];   // K[s0+r][kh*32+..]  (B-operand of S)
    __shared__ bf16 Vs[2][64 * 32];   // V^T[d][s0+kh*32+..] (B-operand of PV)
    __shared__ bf16 Ps[2][64 * 40];   // P[q][s-local], +8 pad vs 32 (bank spread)
    __shared__ float rs_lds[2][64];

    // staging: dest byte offset == tid*16 (linear, required by global_load_lds)
    const int srow = tid >> 2;        // 0..63
    const int scol = (tid & 3) * 8;   // 0,8,16,24

    // Q fragments (A-operand), persistent across both sweeps
    bf16x8 af[2][2];
    #pragma unroll
    for (int mt = 0; mt < 2; ++mt) {
        const int q = m0 + wq * 32 + mt * 16 + c;
        #pragma unroll
        for (int kh = 0; kh < 2; ++kh)
            af[mt][kh] = *(const bf16x8*)(qbase + (size_t)q * 64 + kh * 32 + quad * 8);
    }

    // ---- sweep 1: row sums of exp(score) ----
    float priv[2][4];
    #pragma unroll
    for (int mt = 0; mt < 2; ++mt)
        #pragma unroll
        for (int i = 0; i < 4; ++i) priv[mt][i] = 0.f;

    for (int s0 = 0; s0 < 1024; s0 += 64) {
        __syncthreads();
        gld_lds16(kbase + (size_t)(s0 + srow) * 64 + scol,      &Ks[0][srow * 32 + scol]);
        gld_lds16(kbase + (size_t)(s0 + srow) * 64 + 32 + scol, &Ks[1][srow * 32 + scol]);
        __syncthreads();

        f32x4 acc[2][2];
        #pragma unroll
        for (int mt = 0; mt < 2; ++mt)
            #pragma unroll
            for (int nt = 0; nt < 2; ++nt) acc[mt][nt] = (f32x4){0.f, 0.f, 0.f, 0.f};
        #pragma unroll
        for (int nt = 0; nt < 2; ++nt) {
            const int sr = ws * 32 + nt * 16 + c;
            #pragma unroll
            for (int kh = 0; kh < 2; ++kh) {
                bf16x8 bv = *(const bf16x8*)&Ks[kh][sr * 32 + quad * 8];
                #pragma unroll
                for (int mt = 0; mt < 2; ++mt)
                    acc[mt][nt] = MFMA16(af[mt][kh], bv, acc[mt][nt]);
            }
        }
        #pragma unroll
        for (int mt = 0; mt < 2; ++mt) {
            #pragma unroll
            for (int i = 0; i < 4; ++i) {
                const int q = m0 + wq * 32 + mt * 16 + quad * 4 + i;
                const float* lrow = lps + (size_t)q * 1024 + s0 + ws * 32;
                const unsigned char* mrow = mbase + (size_t)q * 1024 + s0 + ws * 32;
                float t = 0.f;
                #pragma unroll
                for (int nt = 0; nt < 2; ++nt) {
                    float sc = acc[mt][nt][i] * 0.125f + cw * lrow[nt * 16 + c] + cbv;
                    if (mrow[nt * 16 + c]) sc = -1e9f;
                    t += __expf(sc);
                }
                priv[mt][i] += t;
            }
        }
    }
    // reduce across the 16 c-lanes (stays within quad), then across ws waves
    #pragma unroll
    for (int mt = 0; mt < 2; ++mt)
        #pragma unroll
        for (int i = 0; i < 4; ++i) {
            float v = priv[mt][i];
            v += __shfl_xor(v, 1); v += __shfl_xor(v, 2);
            v += __shfl_xor(v, 4); v += __shfl_xor(v, 8);
            priv[mt][i] = v;
        }
    if (c == 0) {
        #pragma unroll
        for (int mt = 0; mt < 2; ++mt)
            #pragma unroll
            for (int i = 0; i < 4; ++i)
                rs_lds[ws][wq * 32 + mt * 16 + quad * 4 + i] = priv[mt][i];
    }
    __syncthreads();
    float rl[2][4];
    #pragma unroll
    for (int mt = 0; mt < 2; ++mt)
        #pragma unroll
        for (int i = 0; i < 4; ++i) {
            const int r = wq * 32 + mt * 16 + quad * 4 + i;
            rl[mt][i] = 1.0f / (rs_lds[0][r] + rs_lds[1][r]);
        }

    // ---- sweep 2: normalized attn write + PV accumulate ----
    f32x4 acc2[2][2];
    #pragma unroll
    for (int mt = 0; mt < 2; ++mt)
        #pragma unroll
        for (int nt = 0; nt < 2; ++nt) acc2[mt][nt] = (f32x4){0.f, 0.f, 0.f, 0.f};

    for (int s0 = 0; s0 < 1024; s0 += 64) {
        __syncthreads();
        gld_lds16(kbase + (size_t)(s0 + srow) * 64 + scol,        &Ks[0][srow * 32 + scol]);
        gld_lds16(kbase + (size_t)(s0 + srow) * 64 + 32 + scol,   &Ks[1][srow * 32 + scol]);
        gld_lds16(vbase + (size_t)srow * 1024 + s0 + scol,        &Vs[0][srow * 32 + scol]);
        gld_lds16(vbase + (size_t)srow * 1024 + s0 + 32 + scol,   &Vs[1][srow * 32 + scol]);
        __syncthreads();

        f32x4 acc[2][2];
        #pragma unroll
        for (int mt = 0; mt < 2; ++mt)
            #pragma unroll
            for (int nt = 0; nt < 2; ++nt) acc[mt][nt] = (f32x4){0.f, 0.f, 0.f, 0.f};
        #pragma unroll
        for (int nt = 0; nt < 2; ++nt) {
            const int sr = ws * 32 + nt * 16 + c;
            #pragma unroll
            for (int kh = 0; kh < 2; ++kh) {
                bf16x8 bv = *(const bf16x8*)&Ks[kh][sr * 32 + quad * 8];
                #pragma unroll
                for (int mt = 0; mt < 2; ++mt)
                    acc[mt][nt] = MFMA16(af[mt][kh], bv, acc[mt][nt]);
            }
        }
        #pragma unroll
        for (int mt = 0; mt < 2; ++mt) {
            #pragma unroll
            for (int i = 0; i < 4; ++i) {
                const int q = m0 + wq * 32 + mt * 16 + quad * 4 + i;
                const int ql = wq * 32 + mt * 16 + quad * 4 + i;
                const float* lrow = lps + (size_t)q * 1024 + s0 + ws * 32;
                const unsigned char* mrow = mbase + (size_t)q * 1024 + s0 + ws * 32;
                float* arow = abase + (size_t)q * 1024 + s0 + ws * 32;
                #pragma unroll
                for (int nt = 0; nt < 2; ++nt) {
                    float sc = acc[mt][nt][i] * 0.125f + cw * lrow[nt * 16 + c] + cbv;
                    if (mrow[nt * 16 + c]) sc = -1e9f;
                    float e = __expf(sc);
                    arow[nt * 16 + c] = e * rl[mt][i];
                    Ps[ws][ql * 40 + nt * 16 + c] = (bf16)e;
                }
            }
        }
        __syncthreads();
        #pragma unroll
        for (int kh = 0; kh < 2; ++kh) {
            bf16x8 a2[2], b2[2];
            #pragma unroll
            for (int mt = 0; mt < 2; ++mt)
                a2[mt] = *(const bf16x8*)&Ps[kh][(wq * 32 + mt * 16 + c) * 40 + quad * 8];
            #pragma unroll
            for (int nt = 0; nt < 2; ++nt)
                b2[nt] = *(const bf16x8*)&Vs[kh][(ws * 32 + nt * 16 + c) * 32 + quad * 8];
            #pragma unroll
            for (int mt = 0; mt < 2; ++mt)
                #pragma unroll
                for (int nt = 0; nt < 2; ++nt)
                    acc2[mt][nt] = MFMA16(a2[mt], b2[nt], acc2[mt][nt]);
        }
    }

    // ---- ctx epilogue: ctx[q][h*64+d] = (PV * rl) ----
    #pragma unroll
    for (int mt = 0; mt < 2; ++mt)
        #pragma unroll
        for (int nt = 0; nt < 2; ++nt)
            #pragma unroll
            for (int i = 0; i < 4; ++i) {
                const int q = m0 + wq * 32 + mt * 16 + quad * 4 + i;
                const int d = ws * 32 + nt * 16 + c;
                ctxb[((size_t)b * 1024 + q) * 1024 + h * 64 + d] =
                    (bf16)(acc2[mt][nt][i] * rl[mt][i]);
            }
}

// ---------------------------------------------------------------------------
// Kernel 5: out_pre = ctx @ W_fc + input_Q, same m97 GEMM structure.
// ---------------------------------------------------------------------------
__global__ __launch_bounds__(256) void fc_gemm(
    const bf16* __restrict__ ctxb, const bf16* __restrict__ Wt,
    const float* __restrict__ resid, float* __restrict__ outp)
{
    const int n0 = blockIdx.x * 128;
    const int m0 = blockIdx.y * 128;
    const int tid = threadIdx.x, w = tid >> 6, lane = tid & 63;
    const int quad = lane >> 4, c = lane & 15;
    const int wm = w & 1, wn = w >> 1;

    __shared__ bf16 As[128 * 32];
    __shared__ bf16 Bs[128 * 32];

    f32x4 acc[4][4];
    #pragma unroll
    for (int mt = 0; mt < 4; ++mt)
        #pragma unroll
        for (int nt = 0; nt < 4; ++nt) acc[mt][nt] = (f32x4){0.f, 0.f, 0.f, 0.f};

    const int lrow = lane >> 2;
    const int lk = (lane & 3) * 8;

    for (int k0 = 0; k0 < 1024; k0 += 32) {
        #pragma unroll
        for (int half = 0; half < 2; ++half) {
            const int row = half * 64 + w * 16 + lrow;
            gld_lds16(ctxb + (size_t)(m0 + row) * 1024 + k0 + lk, As + row * 32 + lk);
            gld_lds16(Wt + (size_t)(n0 + row) * 1024 + k0 + lk, Bs + row * 32 + lk);
        }
        __syncthreads();
        bf16x8 af[4], bv[4];
        #pragma unroll
        for (int mt = 0; mt < 4; ++mt)
            af[mt] = *(const bf16x8*)&As[(wm * 64 + mt * 16 + c) * 32 + quad * 8];
        #pragma unroll
        for (int nt = 0; nt < 4; ++nt)
            bv[nt] = *(const bf16x8*)&Bs[(wn * 64 + nt * 16 + c) * 32 + quad * 8];
        #pragma unroll
        for (int mt = 0; mt < 4; ++mt)
            #pragma unroll
            for (int nt = 0; nt < 4; ++nt)
                acc[mt][nt] = MFMA16(af[mt], bv[nt], acc[mt][nt]);
        __syncthreads();
    }

    #pragma unroll
    for (int mt = 0; mt < 4; ++mt) {
        const int mb = m0 + wm * 64 + mt * 16 + quad * 4;
        #pragma unroll
        for (int nt = 0; nt < 4; ++nt) {
            const int n = n0 + wn * 64 + nt * 16 + c;
            #pragma unroll
            for (int i = 0; i < 4; ++i) {
                const size_t idx = (size_t)(mb + i) * 1024 + n;
                outp[idx] = acc[mt][nt][i] + resid[idx];
            }
        }
    }
}

// ---------------------------------------------------------------------------
// Kernel 6: LayerNorm over last dim (1024).
// ---------------------------------------------------------------------------
__global__ __launch_bounds__(256) void ln_kernel(
    const float* __restrict__ xp, float* __restrict__ out)
{
    const int row = blockIdx.x, tid = threadIdx.x;
    const float* p = xp + (size_t)row * 1024 + tid * 4;
    float4 x = *(const float4*)p;
    float s = x.x + x.y + x.z + x.w;
    float q = x.x * x.x + x.y * x.y + x.z * x.z + x.w * x.w;
    #pragma unroll
    for (int off = 32; off >= 1; off >>= 1) {
        s += __shfl_down(s, off);
        q += __shfl_down(q, off);
    }
    __shared__ float sb[4], qb[4];
    const int w = tid >> 6, lane = tid & 63;
    if (lane == 0) { sb[w] = s; qb[w] = q; }
    __syncthreads();
    const float ts = sb[0] + sb[1] + sb[2] + sb[3];
    const float tq = qb[0] + qb[1] + qb[2] + qb[3];
    const float mean = ts * (1.0f / 1024.0f);
    const float var = tq * (1.0f / 1024.0f) - mean * mean;
    const float rs = rsqrtf(var + 1e-5f);
    float4 o;
    o.x = (x.x - mean) * rs; o.y = (x.y - mean) * rs;
    o.z = (x.z - mean) * rs; o.w = (x.w - mean) * rs;
    *(float4*)(out + (size_t)row * 1024 + tid * 4) = o;
}

// ---------------------------------------------------------------------------
extern "C" void kernel_launch(void* const* d_in, const int* in_sizes, int n_in,
                              void* d_out, int out_size, void* d_ws, size_t ws_size,
                              hipStream_t stream)
{
    const float* Xq  = (const float*)d_in[0];
    const float* Xk  = (const float*)d_in[1];
    const float* Xv  = (const float*)d_in[2];
    const unsigned char* mask = (const unsigned char*)d_in[3];
    const float* lps = (const float*)d_in[4];
    const float* Wq  = (const float*)d_in[5];
    const float* Wk  = (const float*)d_in[6];
    const float* Wv  = (const float*)d_in[7];
    const float* Wfc = (const float*)d_in[8];
    const float* cw  = (const float*)d_in[9];
    const float* cb  = (const float*)d_in[10];

    char* ws = (char*)d_ws;
    const size_t MB = 1024 * 1024;
    bf16* Wtq = (bf16*)(ws + 0 * MB);
    bf16* Wtk = (bf16*)(ws + 2 * MB);
    bf16* Wtv = (bf16*)(ws + 4 * MB);
    bf16* Wtf = (bf16*)(ws + 6 * MB);
    bf16* Qb  = (bf16*)(ws + 8 * MB);      // [4][16][1024][64]
    bf16* Kb  = (bf16*)(ws + 16 * MB);     // [4][16][1024][64]
    bf16* VT  = (bf16*)(ws + 24 * MB);     // [4][16][64][1024]
    // Xbf lifetime: [xcast, qkv_gemm]; ctx written by attn (later), outp by fc
    bf16* Xbq = (bf16*)(ws + 32 * MB);     // overlaps ctx region
    bf16* Xbk = (bf16*)(ws + 40 * MB);     // overlaps outp region
    bf16* Xbv = (bf16*)(ws + 48 * MB);     // overlaps outp region
    bf16* ctx = (bf16*)(ws + 32 * MB);     // [4096][1024] bf16
    float* outp = (float*)(ws + 40 * MB);  // [4096][1024] f32

    float* out_ln = (float*)d_out;
    float* attn   = (float*)d_out + (size_t)4 * MB;

    wcvt_kernel<<<dim3(16, 16, 4), 256, 0, stream>>>(Wq, Wk, Wv, Wfc, Wtq, Wtk, Wtv, Wtf);
    xcast_kernel<<<dim3(2048, 1, 3), 256, 0, stream>>>(Xq, Xk, Xv, Xbq, Xbk, Xbv);
    qkv_gemm<<<dim3(8, 32, 3), 256, 0, stream>>>(Xbq, Xbk, Xbv, Wtq, Wtk, Wtv, Qb, Kb, VT);
    attn_kernel<<<dim3(16, 16, 4), 256, 0, stream>>>(Qb, Kb, VT, lps, mask, cw, cb, attn, ctx);
    fc_gemm<<<dim3(8, 32, 1), 256, 0, stream>>>(ctx, Wtf, Xq, outp);
    ln_kernel<<<4096, 256, 0, stream>>>(outp, out_ln);
}

// Round 3
// 575.005 us; speedup vs baseline: 1.3256x; 1.1804x over previous
//
#include <hip/hip_runtime.h>
#include <hip/hip_bf16.h>

typedef __bf16 bf16;
typedef __attribute__((ext_vector_type(8))) __bf16 bf16x8;
typedef __attribute__((ext_vector_type(4))) __bf16 bf16x4;
typedef __attribute__((ext_vector_type(4))) float f32x4;

#define MFMA16(a, b, c) __builtin_amdgcn_mfma_f32_16x16x32_bf16((a), (b), (c), 0, 0, 0)

__device__ __forceinline__ void gld_lds16(const bf16* g, bf16* l) {
    __builtin_amdgcn_global_load_lds(
        (const __attribute__((address_space(1))) void*)g,
        (__attribute__((address_space(3))) void*)l, 16, 0, 0);
}

// ---------------------------------------------------------------------------
// Kernel 1: weight transpose + f32->bf16 cast.  W [1024(k)][1024(n)] f32 ->
// Wt [1024(n)][1024(k)] bf16.
// ---------------------------------------------------------------------------
__global__ __launch_bounds__(256) void wcvt_kernel(
    const float* __restrict__ W0, const float* __restrict__ W1,
    const float* __restrict__ W2, const float* __restrict__ W3,
    bf16* __restrict__ T0, bf16* __restrict__ T1,
    bf16* __restrict__ T2, bf16* __restrict__ T3)
{
    const int z = blockIdx.z;
    const float* W = (z == 0) ? W0 : (z == 1) ? W1 : (z == 2) ? W2 : W3;
    bf16* T = (z == 0) ? T0 : (z == 1) ? T1 : (z == 2) ? T2 : T3;
    const int k0 = blockIdx.x * 64, n0 = blockIdx.y * 64;
    const int tid = threadIdx.x;

    __shared__ float tile[64][65];

    #pragma unroll
    for (int rr = 0; rr < 4; ++rr) {
        int r = (tid >> 4) + rr * 16;
        int cg = (tid & 15) * 4;
        float4 v = *(const float4*)(W + (size_t)(k0 + r) * 1024 + n0 + cg);
        tile[r][cg + 0] = v.x; tile[r][cg + 1] = v.y;
        tile[r][cg + 2] = v.z; tile[r][cg + 3] = v.w;
    }
    __syncthreads();

    const int n_local = tid >> 2;
    const int kg = (tid & 3) * 16;
    bf16x8 v0, v1;
    #pragma unroll
    for (int j = 0; j < 8; ++j) v0[j] = (bf16)tile[kg + j][n_local];
    #pragma unroll
    for (int j = 0; j < 8; ++j) v1[j] = (bf16)tile[kg + 8 + j][n_local];
    bf16* dst = T + (size_t)(n0 + n_local) * 1024 + k0 + kg;
    *(bf16x8*)dst = v0;
    *(bf16x8*)(dst + 8) = v1;
}

// ---------------------------------------------------------------------------
// Kernel 2: X f32 -> bf16 cast (enables global_load_lds staging in the GEMM).
// ---------------------------------------------------------------------------
__global__ __launch_bounds__(256) void xcast_kernel(
    const float* __restrict__ Xq, const float* __restrict__ Xk, const float* __restrict__ Xv,
    bf16* __restrict__ Yq, bf16* __restrict__ Yk, bf16* __restrict__ Yv)
{
    const int z = blockIdx.z;
    const float* X = (z == 0) ? Xq : (z == 1) ? Xk : Xv;
    bf16* Y = (z == 0) ? Yq : (z == 1) ? Yk : Yv;
    const size_t i = ((size_t)blockIdx.x * 256 + threadIdx.x) * 8;
    float4 a = *(const float4*)(X + i);
    float4 b = *(const float4*)(X + i + 4);
    bf16x8 o = {(bf16)a.x, (bf16)a.y, (bf16)a.z, (bf16)a.w,
                (bf16)b.x, (bf16)b.y, (bf16)b.z, (bf16)b.w};
    *(bf16x8*)(Y + i) = o;
}

// ---------------------------------------------------------------------------
// Kernel 3: QKV projection, m97-style. 128x128 tile, 4 waves (each 64x64),
// LDS staging via global_load_lds width=16, K-step 32.
// ---------------------------------------------------------------------------
__global__ __launch_bounds__(256) void qkv_gemm(
    const bf16* __restrict__ Xq, const bf16* __restrict__ Xk, const bf16* __restrict__ Xv,
    const bf16* __restrict__ Wtq, const bf16* __restrict__ Wtk, const bf16* __restrict__ Wtv,
    bf16* __restrict__ Qb, bf16* __restrict__ Kb, bf16* __restrict__ VT)
{
    const int z = blockIdx.z;
    const bf16* X = (z == 0) ? Xq : (z == 1) ? Xk : Xv;
    const bf16* Wt = (z == 0) ? Wtq : (z == 1) ? Wtk : Wtv;
    const int n0 = blockIdx.x * 128;
    const int m0 = blockIdx.y * 128;
    const int tid = threadIdx.x, w = tid >> 6, lane = tid & 63;
    const int quad = lane >> 4, c = lane & 15;
    const int wm = w & 1, wn = w >> 1;

    __shared__ bf16 As[128 * 32];
    __shared__ bf16 Bs[128 * 32];

    f32x4 acc[4][4];
    #pragma unroll
    for (int mt = 0; mt < 4; ++mt)
        #pragma unroll
        for (int nt = 0; nt < 4; ++nt) acc[mt][nt] = (f32x4){0.f, 0.f, 0.f, 0.f};

    const int lrow = lane >> 2;        // 0..15
    const int lk = (lane & 3) * 8;     // 0,8,16,24

    for (int k0 = 0; k0 < 1024; k0 += 32) {
        #pragma unroll
        for (int half = 0; half < 2; ++half) {
            const int row = half * 64 + w * 16 + lrow;
            gld_lds16(X + (size_t)(m0 + row) * 1024 + k0 + lk, As + row * 32 + lk);
            gld_lds16(Wt + (size_t)(n0 + row) * 1024 + k0 + lk, Bs + row * 32 + lk);
        }
        __syncthreads();
        bf16x8 af[4], bv[4];
        #pragma unroll
        for (int mt = 0; mt < 4; ++mt)
            af[mt] = *(const bf16x8*)&As[(wm * 64 + mt * 16 + c) * 32 + quad * 8];
        #pragma unroll
        for (int nt = 0; nt < 4; ++nt)
            bv[nt] = *(const bf16x8*)&Bs[(wn * 64 + nt * 16 + c) * 32 + quad * 8];
        #pragma unroll
        for (int mt = 0; mt < 4; ++mt)
            #pragma unroll
            for (int nt = 0; nt < 4; ++nt)
                acc[mt][nt] = MFMA16(af[mt], bv[nt], acc[mt][nt]);
        __syncthreads();
    }

    #pragma unroll
    for (int mt = 0; mt < 4; ++mt) {
        const int mb = m0 + wm * 64 + mt * 16 + quad * 4;
        const int b = mb >> 10, s = mb & 1023;
        #pragma unroll
        for (int nt = 0; nt < 4; ++nt) {
            const int n = n0 + wn * 64 + nt * 16 + c;
            const int h = n >> 6, d = n & 63;
            if (z == 2) {
                bf16x4 v = {(bf16)acc[mt][nt][0], (bf16)acc[mt][nt][1],
                            (bf16)acc[mt][nt][2], (bf16)acc[mt][nt][3]};
                *(bf16x4*)(VT + ((size_t)(b * 16 + h) * 64 + d) * 1024 + s) = v;
            } else {
                bf16* dst = ((z == 0) ? Qb : Kb) + ((size_t)(b * 16 + h) * 1024 + s) * 64 + d;
                #pragma unroll
                for (int i = 0; i < 4; ++i) dst[(size_t)i * 64] = (bf16)acc[mt][nt][i];
            }
        }
    }
}

// ---------------------------------------------------------------------------
// Kernel 4: single-sweep deferred-normalization attention.
// Per block: 32 q-rows x all 1024 keys, 4 waves (wq = q-half 16 rows;
// ws = key-half for QK^T, d-half for PV).  One pass per 64-key tile:
// stage K+V -> QK^T -> exp -> store unnormalized P (bf16) into a 64KB
// XOR-swizzled LDS buffer + accumulate row sums -> PV MFMA from LDS.
// K tile for t+1 prefetched under PV (K buffer dead after P write barrier).
// Epilogue: rl = 1/sum; ctx = PV*rl; attn rows streamed LDS->global as
// coalesced f32x4 (one row per pass).
// vs Round 2: removes the duplicate QK^T sweep (2x MFMA/exp/lps/mask),
// half the K staging, half the barriers.  LDS = 64+8+8 = 80 KB exactly
// -> 2 blocks/CU.  P swizzle: byte ^= (row&7)<<4 (2-way max on b128 reads).
// ---------------------------------------------------------------------------
__global__ __launch_bounds__(256) void attn_kernel(
    const bf16* __restrict__ Qb, const bf16* __restrict__ Kb, const bf16* __restrict__ VT,
    const float* __restrict__ lps, const unsigned char* __restrict__ mask,
    const float* __restrict__ cwp, const float* __restrict__ cbp,
    float* __restrict__ attn, bf16* __restrict__ ctxb)
{
    const int qt = blockIdx.x, h = blockIdx.y, b = blockIdx.z;
    const int tid = threadIdx.x, w = tid >> 6, lane = tid & 63;
    const int quad = lane >> 4, c = lane & 15;
    const int wq = w & 1, ws = w >> 1;
    const float cw = cwp[0], cbv = cbp[0];
    const int m0 = qt * 32;
    const size_t bh = (size_t)(b * 16 + h);

    const bf16* qbase = Qb + bh * 1024 * 64;
    const bf16* kbase = Kb + bh * 1024 * 64;
    const bf16* vbase = VT + bh * 64 * 1024;
    const unsigned char* mbase = mask + (size_t)b * 1024 * 1024;
    float* abase = attn + bh * 1024 * 1024;

    __shared__ __align__(16) char PsRaw[32 * 2048];  // 64 KB unnormalized P (bf16)
    __shared__ bf16 Ks[2][64 * 32];                   // 8 KB [kh_d][key][d']
    __shared__ bf16 Vs[2][64 * 32];                   // 8 KB [kh_s][d][s']

    // staging: linear dest = tid*16 bytes per buffer half
    const int skey = tid >> 2;         // 0..63 (key for K, d for V)
    const int sch = (tid & 3) * 8;     // element offset of this thread's 16B

    // Q fragments (A-operand), persistent
    bf16x8 af[2];
    #pragma unroll
    for (int kh = 0; kh < 2; ++kh)
        af[kh] = *(const bf16x8*)(qbase + (size_t)(m0 + wq * 16 + c) * 64 + kh * 32 + quad * 8);

    // prologue: stage tile 0
    #pragma unroll
    for (int kh = 0; kh < 2; ++kh) {
        gld_lds16(kbase + (size_t)skey * 64 + kh * 32 + sch, &Ks[kh][skey * 32 + sch]);
        gld_lds16(vbase + (size_t)skey * 1024 + kh * 32 + sch, &Vs[kh][skey * 32 + sch]);
    }

    f32x4 acc2[2];
    acc2[0] = (f32x4){0.f, 0.f, 0.f, 0.f};
    acc2[1] = (f32x4){0.f, 0.f, 0.f, 0.f};
    float priv[4] = {0.f, 0.f, 0.f, 0.f};

    for (int t = 0; t < 16; ++t) {
        const int s0 = t * 64;
        __syncthreads();   // staging of tile t complete (vmcnt drained)

        // ---- QK^T: S[q][key], q rows wq*16.., keys ws*32.. ----
        f32x4 sacc[2];
        sacc[0] = (f32x4){0.f, 0.f, 0.f, 0.f};
        sacc[1] = (f32x4){0.f, 0.f, 0.f, 0.f};
        #pragma unroll
        for (int nt = 0; nt < 2; ++nt)
            #pragma unroll
            for (int kh = 0; kh < 2; ++kh) {
                bf16x8 bv = *(const bf16x8*)&Ks[kh][(ws * 32 + nt * 16 + c) * 32 + quad * 8];
                sacc[nt] = MFMA16(af[kh], bv, sacc[nt]);
            }

        // ---- score -> exp -> P(LDS) + row-sum ----
        #pragma unroll
        for (int i = 0; i < 4; ++i) {
            const int row = wq * 16 + quad * 4 + i;
            const int q = m0 + row;
            const float* lrow = lps + (size_t)q * 1024 + s0 + ws * 32;
            const unsigned char* mrow = mbase + (size_t)q * 1024 + s0 + ws * 32;
            const int swz = (row & 7) << 4;
            #pragma unroll
            for (int nt = 0; nt < 2; ++nt) {
                const int col = s0 + ws * 32 + nt * 16 + c;
                float sc = sacc[nt][i] * 0.125f + cw * lrow[nt * 16 + c] + cbv;
                if (mrow[nt * 16 + c]) sc = -1e9f;
                float e = __expf(sc);
                priv[i] += e;
                *(bf16*)(PsRaw + row * 2048 + ((col * 2) ^ swz)) = (bf16)e;
            }
        }
        __syncthreads();   // P(t) visible; Ks dead

        // prefetch K(t+1) under PV
        if (t < 15) {
            #pragma unroll
            for (int kh = 0; kh < 2; ++kh)
                gld_lds16(kbase + (size_t)(s0 + 64 + skey) * 64 + kh * 32 + sch,
                          &Ks[kh][skey * 32 + sch]);
        }

        // ---- PV: ctx[q][d] += P[q][s] V[s][d], d half = ws ----
        const int prow = wq * 16 + c;
        const int pswz = (prow & 7) << 4;
        #pragma unroll
        for (int kh = 0; kh < 2; ++kh) {
            bf16x8 a2 = *(const bf16x8*)(PsRaw + prow * 2048 +
                                         (((s0 + kh * 32 + quad * 8) * 2) ^ pswz));
            #pragma unroll
            for (int nt = 0; nt < 2; ++nt) {
                bf16x8 b2v = *(const bf16x8*)&Vs[kh][(ws * 32 + nt * 16 + c) * 32 + quad * 8];
                acc2[nt] = MFMA16(a2, b2v, acc2[nt]);
            }
        }
        __syncthreads();   // PV reads done; Vs dead

        // stage V(t+1)
        if (t < 15) {
            #pragma unroll
            for (int kh = 0; kh < 2; ++kh)
                gld_lds16(vbase + (size_t)skey * 1024 + s0 + 64 + kh * 32 + sch,
                          &Vs[kh][skey * 32 + sch]);
        }
    }

    // ---- row-sum combine across ws pair (Ks reused as scratch) ----
    float* rsp = (float*)&Ks[0][0];    // [2][32]
    float* rlz = rsp + 64;             // [32]
    #pragma unroll
    for (int i = 0; i < 4; ++i) {
        float v = priv[i];
        v += __shfl_xor(v, 1); v += __shfl_xor(v, 2);
        v += __shfl_xor(v, 4); v += __shfl_xor(v, 8);
        priv[i] = v;
    }
    if (c == 0) {
        #pragma unroll
        for (int i = 0; i < 4; ++i)
            rsp[ws * 32 + wq * 16 + quad * 4 + i] = priv[i];
    }
    __syncthreads();
    if (tid < 32) rlz[tid] = 1.0f / (rsp[tid] + rsp[32 + tid]);
    __syncthreads();

    // ---- ctx epilogue ----
    #pragma unroll
    for (int nt = 0; nt < 2; ++nt)
        #pragma unroll
        for (int i = 0; i < 4; ++i) {
            const int row = wq * 16 + quad * 4 + i;
            const int q = m0 + row;
            const int d = ws * 32 + nt * 16 + c;
            ctxb[((size_t)b * 1024 + q) * 1024 + h * 64 + d] = (bf16)(acc2[nt][i] * rlz[row]);
        }

    // ---- attn write: one q-row per pass, coalesced f32x4 ----
    for (int p = 0; p < 32; ++p) {
        const float rl = rlz[p];
        bf16x4 pv = *(const bf16x4*)(PsRaw + p * 2048 + ((tid * 8) ^ ((p & 7) << 4)));
        float4 o = {(float)pv[0] * rl, (float)pv[1] * rl,
                    (float)pv[2] * rl, (float)pv[3] * rl};
        *(float4*)(abase + (size_t)(m0 + p) * 1024 + tid * 4) = o;
    }
}

// ---------------------------------------------------------------------------
// Kernel 5: out_pre = ctx @ W_fc + input_Q, same m97 GEMM structure.
// ---------------------------------------------------------------------------
__global__ __launch_bounds__(256) void fc_gemm(
    const bf16* __restrict__ ctxb, const bf16* __restrict__ Wt,
    const float* __restrict__ resid, float* __restrict__ outp)
{
    const int n0 = blockIdx.x * 128;
    const int m0 = blockIdx.y * 128;
    const int tid = threadIdx.x, w = tid >> 6, lane = tid & 63;
    const int quad = lane >> 4, c = lane & 15;
    const int wm = w & 1, wn = w >> 1;

    __shared__ bf16 As[128 * 32];
    __shared__ bf16 Bs[128 * 32];

    f32x4 acc[4][4];
    #pragma unroll
    for (int mt = 0; mt < 4; ++mt)
        #pragma unroll
        for (int nt = 0; nt < 4; ++nt) acc[mt][nt] = (f32x4){0.f, 0.f, 0.f, 0.f};

    const int lrow = lane >> 2;
    const int lk = (lane & 3) * 8;

    for (int k0 = 0; k0 < 1024; k0 += 32) {
        #pragma unroll
        for (int half = 0; half < 2; ++half) {
            const int row = half * 64 + w * 16 + lrow;
            gld_lds16(ctxb + (size_t)(m0 + row) * 1024 + k0 + lk, As + row * 32 + lk);
            gld_lds16(Wt + (size_t)(n0 + row) * 1024 + k0 + lk, Bs + row * 32 + lk);
        }
        __syncthreads();
        bf16x8 af[4], bv[4];
        #pragma unroll
        for (int mt = 0; mt < 4; ++mt)
            af[mt] = *(const bf16x8*)&As[(wm * 64 + mt * 16 + c) * 32 + quad * 8];
        #pragma unroll
        for (int nt = 0; nt < 4; ++nt)
            bv[nt] = *(const bf16x8*)&Bs[(wn * 64 + nt * 16 + c) * 32 + quad * 8];
        #pragma unroll
        for (int mt = 0; mt < 4; ++mt)
            #pragma unroll
            for (int nt = 0; nt < 4; ++nt)
                acc[mt][nt] = MFMA16(af[mt], bv[nt], acc[mt][nt]);
        __syncthreads();
    }

    #pragma unroll
    for (int mt = 0; mt < 4; ++mt) {
        const int mb = m0 + wm * 64 + mt * 16 + quad * 4;
        #pragma unroll
        for (int nt = 0; nt < 4; ++nt) {
            const int n = n0 + wn * 64 + nt * 16 + c;
            #pragma unroll
            for (int i = 0; i < 4; ++i) {
                const size_t idx = (size_t)(mb + i) * 1024 + n;
                outp[idx] = acc[mt][nt][i] + resid[idx];
            }
        }
    }
}

// ---------------------------------------------------------------------------
// Kernel 6: LayerNorm over last dim (1024).
// ---------------------------------------------------------------------------
__global__ __launch_bounds__(256) void ln_kernel(
    const float* __restrict__ xp, float* __restrict__ out)
{
    const int row = blockIdx.x, tid = threadIdx.x;
    const float* p = xp + (size_t)row * 1024 + tid * 4;
    float4 x = *(const float4*)p;
    float s = x.x + x.y + x.z + x.w;
    float q = x.x * x.x + x.y * x.y + x.z * x.z + x.w * x.w;
    #pragma unroll
    for (int off = 32; off >= 1; off >>= 1) {
        s += __shfl_down(s, off);
        q += __shfl_down(q, off);
    }
    __shared__ float sb[4], qb[4];
    const int w = tid >> 6, lane = tid & 63;
    if (lane == 0) { sb[w] = s; qb[w] = q; }
    __syncthreads();
    const float ts = sb[0] + sb[1] + sb[2] + sb[3];
    const float tq = qb[0] + qb[1] + qb[2] + qb[3];
    const float mean = ts * (1.0f / 1024.0f);
    const float var = tq * (1.0f / 1024.0f) - mean * mean;
    const float rs = rsqrtf(var + 1e-5f);
    float4 o;
    o.x = (x.x - mean) * rs; o.y = (x.y - mean) * rs;
    o.z = (x.z - mean) * rs; o.w = (x.w - mean) * rs;
    *(float4*)(out + (size_t)row * 1024 + tid * 4) = o;
}

// ---------------------------------------------------------------------------
extern "C" void kernel_launch(void* const* d_in, const int* in_sizes, int n_in,
                              void* d_out, int out_size, void* d_ws, size_t ws_size,
                              hipStream_t stream)
{
    const float* Xq  = (const float*)d_in[0];
    const float* Xk  = (const float*)d_in[1];
    const float* Xv  = (const float*)d_in[2];
    const unsigned char* mask = (const unsigned char*)d_in[3];
    const float* lps = (const float*)d_in[4];
    const float* Wq  = (const float*)d_in[5];
    const float* Wk  = (const float*)d_in[6];
    const float* Wv  = (const float*)d_in[7];
    const float* Wfc = (const float*)d_in[8];
    const float* cw  = (const float*)d_in[9];
    const float* cb  = (const float*)d_in[10];

    char* ws = (char*)d_ws;
    const size_t MB = 1024 * 1024;
    bf16* Wtq = (bf16*)(ws + 0 * MB);
    bf16* Wtk = (bf16*)(ws + 2 * MB);
    bf16* Wtv = (bf16*)(ws + 4 * MB);
    bf16* Wtf = (bf16*)(ws + 6 * MB);
    bf16* Qb  = (bf16*)(ws + 8 * MB);      // [4][16][1024][64]
    bf16* Kb  = (bf16*)(ws + 16 * MB);     // [4][16][1024][64]
    bf16* VT  = (bf16*)(ws + 24 * MB);     // [4][16][64][1024]
    // Xbf lifetime: [xcast, qkv_gemm]; ctx written by attn (later), outp by fc
    bf16* Xbq = (bf16*)(ws + 32 * MB);     // overlaps ctx region
    bf16* Xbk = (bf16*)(ws + 40 * MB);     // overlaps outp region
    bf16* Xbv = (bf16*)(ws + 48 * MB);     // overlaps outp region
    bf16* ctx = (bf16*)(ws + 32 * MB);     // [4096][1024] bf16
    float* outp = (float*)(ws + 40 * MB);  // [4096][1024] f32

    float* out_ln = (float*)d_out;
    float* attn   = (float*)d_out + (size_t)4 * MB;

    wcvt_kernel<<<dim3(16, 16, 4), 256, 0, stream>>>(Wq, Wk, Wv, Wfc, Wtq, Wtk, Wtv, Wtf);
    xcast_kernel<<<dim3(2048, 1, 3), 256, 0, stream>>>(Xq, Xk, Xv, Xbq, Xbk, Xbv);
    qkv_gemm<<<dim3(8, 32, 3), 256, 0, stream>>>(Xbq, Xbk, Xbv, Wtq, Wtk, Wtv, Qb, Kb, VT);
    attn_kernel<<<dim3(32, 16, 4), 256, 0, stream>>>(Qb, Kb, VT, lps, mask, cw, cb, attn, ctx);
    fc_gemm<<<dim3(8, 32, 1), 256, 0, stream>>>(ctx, Wtf, Xq, outp);
    ln_kernel<<<4096, 256, 0, stream>>>(outp, out_ln);
}

// Round 4
// 564.901 us; speedup vs baseline: 1.3493x; 1.0179x over previous
//
#include <hip/hip_runtime.h>
#include <hip/hip_bf16.h>

typedef __bf16 bf16;
typedef __attribute__((ext_vector_type(8))) __bf16 bf16x8;
typedef __attribute__((ext_vector_type(4))) __bf16 bf16x4;
typedef __attribute__((ext_vector_type(4))) float f32x4;

#define MFMA16(a, b, c) __builtin_amdgcn_mfma_f32_16x16x32_bf16((a), (b), (c), 0, 0, 0)

__device__ __forceinline__ void gld_lds16(const bf16* g, bf16* l) {
    __builtin_amdgcn_global_load_lds(
        (const __attribute__((address_space(1))) void*)g,
        (__attribute__((address_space(3))) void*)l, 16, 0, 0);
}

#define WAIT_VM2()   asm volatile("s_waitcnt vmcnt(2)" ::: "memory")
#define WAIT_VM0()   asm volatile("s_waitcnt vmcnt(0)" ::: "memory")
#define WAIT_LGKM0() asm volatile("s_waitcnt lgkmcnt(0)" ::: "memory")
#define SBAR()       __builtin_amdgcn_s_barrier()
#define SFENCE()     __builtin_amdgcn_sched_barrier(0)

// ---------------------------------------------------------------------------
// Kernel 1: weight transpose + f32->bf16 cast.  W [1024(k)][1024(n)] f32 ->
// Wt [1024(n)][1024(k)] bf16.
// ---------------------------------------------------------------------------
__global__ __launch_bounds__(256) void wcvt_kernel(
    const float* __restrict__ W0, const float* __restrict__ W1,
    const float* __restrict__ W2, const float* __restrict__ W3,
    bf16* __restrict__ T0, bf16* __restrict__ T1,
    bf16* __restrict__ T2, bf16* __restrict__ T3)
{
    const int z = blockIdx.z;
    const float* W = (z == 0) ? W0 : (z == 1) ? W1 : (z == 2) ? W2 : W3;
    bf16* T = (z == 0) ? T0 : (z == 1) ? T1 : (z == 2) ? T2 : T3;
    const int k0 = blockIdx.x * 64, n0 = blockIdx.y * 64;
    const int tid = threadIdx.x;

    __shared__ float tile[64][65];

    #pragma unroll
    for (int rr = 0; rr < 4; ++rr) {
        int r = (tid >> 4) + rr * 16;
        int cg = (tid & 15) * 4;
        float4 v = *(const float4*)(W + (size_t)(k0 + r) * 1024 + n0 + cg);
        tile[r][cg + 0] = v.x; tile[r][cg + 1] = v.y;
        tile[r][cg + 2] = v.z; tile[r][cg + 3] = v.w;
    }
    __syncthreads();

    const int n_local = tid >> 2;
    const int kg = (tid & 3) * 16;
    bf16x8 v0, v1;
    #pragma unroll
    for (int j = 0; j < 8; ++j) v0[j] = (bf16)tile[kg + j][n_local];
    #pragma unroll
    for (int j = 0; j < 8; ++j) v1[j] = (bf16)tile[kg + 8 + j][n_local];
    bf16* dst = T + (size_t)(n0 + n_local) * 1024 + k0 + kg;
    *(bf16x8*)dst = v0;
    *(bf16x8*)(dst + 8) = v1;
}

// ---------------------------------------------------------------------------
// Kernel 2: X f32 -> bf16 cast (enables global_load_lds staging in the GEMM).
// ---------------------------------------------------------------------------
__global__ __launch_bounds__(256) void xcast_kernel(
    const float* __restrict__ Xq, const float* __restrict__ Xk, const float* __restrict__ Xv,
    bf16* __restrict__ Yq, bf16* __restrict__ Yk, bf16* __restrict__ Yv)
{
    const int z = blockIdx.z;
    const float* X = (z == 0) ? Xq : (z == 1) ? Xk : Xv;
    bf16* Y = (z == 0) ? Yq : (z == 1) ? Yk : Yv;
    const size_t i = ((size_t)blockIdx.x * 256 + threadIdx.x) * 8;
    float4 a = *(const float4*)(X + i);
    float4 b = *(const float4*)(X + i + 4);
    bf16x8 o = {(bf16)a.x, (bf16)a.y, (bf16)a.z, (bf16)a.w,
                (bf16)b.x, (bf16)b.y, (bf16)b.z, (bf16)b.w};
    *(bf16x8*)(Y + i) = o;
}

// ---------------------------------------------------------------------------
// Kernel 3: QKV projection, m97-style. 128x128 tile, 4 waves (each 64x64),
// LDS staging via global_load_lds width=16, K-step 32.
// ---------------------------------------------------------------------------
__global__ __launch_bounds__(256) void qkv_gemm(
    const bf16* __restrict__ Xq, const bf16* __restrict__ Xk, const bf16* __restrict__ Xv,
    const bf16* __restrict__ Wtq, const bf16* __restrict__ Wtk, const bf16* __restrict__ Wtv,
    bf16* __restrict__ Qb, bf16* __restrict__ Kb, bf16* __restrict__ VT)
{
    const int z = blockIdx.z;
    const bf16* X = (z == 0) ? Xq : (z == 1) ? Xk : Xv;
    const bf16* Wt = (z == 0) ? Wtq : (z == 1) ? Wtk : Wtv;
    const int n0 = blockIdx.x * 128;
    const int m0 = blockIdx.y * 128;
    const int tid = threadIdx.x, w = tid >> 6, lane = tid & 63;
    const int quad = lane >> 4, c = lane & 15;
    const int wm = w & 1, wn = w >> 1;

    __shared__ bf16 As[128 * 32];
    __shared__ bf16 Bs[128 * 32];

    f32x4 acc[4][4];
    #pragma unroll
    for (int mt = 0; mt < 4; ++mt)
        #pragma unroll
        for (int nt = 0; nt < 4; ++nt) acc[mt][nt] = (f32x4){0.f, 0.f, 0.f, 0.f};

    const int lrow = lane >> 2;        // 0..15
    const int lk = (lane & 3) * 8;     // 0,8,16,24

    for (int k0 = 0; k0 < 1024; k0 += 32) {
        #pragma unroll
        for (int half = 0; half < 2; ++half) {
            const int row = half * 64 + w * 16 + lrow;
            gld_lds16(X + (size_t)(m0 + row) * 1024 + k0 + lk, As + row * 32 + lk);
            gld_lds16(Wt + (size_t)(n0 + row) * 1024 + k0 + lk, Bs + row * 32 + lk);
        }
        __syncthreads();
        bf16x8 af[4], bv[4];
        #pragma unroll
        for (int mt = 0; mt < 4; ++mt)
            af[mt] = *(const bf16x8*)&As[(wm * 64 + mt * 16 + c) * 32 + quad * 8];
        #pragma unroll
        for (int nt = 0; nt < 4; ++nt)
            bv[nt] = *(const bf16x8*)&Bs[(wn * 64 + nt * 16 + c) * 32 + quad * 8];
        #pragma unroll
        for (int mt = 0; mt < 4; ++mt)
            #pragma unroll
            for (int nt = 0; nt < 4; ++nt)
                acc[mt][nt] = MFMA16(af[mt], bv[nt], acc[mt][nt]);
        __syncthreads();
    }

    #pragma unroll
    for (int mt = 0; mt < 4; ++mt) {
        const int mb = m0 + wm * 64 + mt * 16 + quad * 4;
        const int b = mb >> 10, s = mb & 1023;
        #pragma unroll
        for (int nt = 0; nt < 4; ++nt) {
            const int n = n0 + wn * 64 + nt * 16 + c;
            const int h = n >> 6, d = n & 63;
            if (z == 2) {
                bf16x4 v = {(bf16)acc[mt][nt][0], (bf16)acc[mt][nt][1],
                            (bf16)acc[mt][nt][2], (bf16)acc[mt][nt][3]};
                *(bf16x4*)(VT + ((size_t)(b * 16 + h) * 64 + d) * 1024 + s) = v;
            } else {
                bf16* dst = ((z == 0) ? Qb : Kb) + ((size_t)(b * 16 + h) * 1024 + s) * 64 + d;
                #pragma unroll
                for (int i = 0; i < 4; ++i) dst[(size_t)i * 64] = (bf16)acc[mt][nt][i];
            }
        }
    }
}

// ---------------------------------------------------------------------------
// Kernel 4: single-sweep deferred-normalization attention with counted-vmcnt
// software pipeline (T4).  Same dataflow as Round 3; __syncthreads (which
// drains vmcnt(0) and killed all prefetch overlap -- two full memory
// latencies exposed per tile) replaced by raw s_barrier + counted s_waitcnt:
//   bar1: vmcnt(2)            -> K(t) in LDS, V(t) still in flight
//   bar2: lgkmcnt(0)+vmcnt(0) -> P visible, V(t) in, Ks free; issue K(t+1)
//   bar3: lgkmcnt(0)          -> Vs free; issue V(t+1)
// K(t+1) hides under PV+bar3; V(t+1) hides under bar1+QK^T+exp.
// Per-thread issue order is always K-pair then V-pair so the vmcnt FIFO
// counts are exact.
// ---------------------------------------------------------------------------
__global__ __launch_bounds__(256) void attn_kernel(
    const bf16* __restrict__ Qb, const bf16* __restrict__ Kb, const bf16* __restrict__ VT,
    const float* __restrict__ lps, const unsigned char* __restrict__ mask,
    const float* __restrict__ cwp, const float* __restrict__ cbp,
    float* __restrict__ attn, bf16* __restrict__ ctxb)
{
    const int qt = blockIdx.x, h = blockIdx.y, b = blockIdx.z;
    const int tid = threadIdx.x, w = tid >> 6, lane = tid & 63;
    const int quad = lane >> 4, c = lane & 15;
    const int wq = w & 1, ws = w >> 1;
    const float cw = cwp[0], cbv = cbp[0];
    const int m0 = qt * 32;
    const size_t bh = (size_t)(b * 16 + h);

    const bf16* qbase = Qb + bh * 1024 * 64;
    const bf16* kbase = Kb + bh * 1024 * 64;
    const bf16* vbase = VT + bh * 64 * 1024;
    const unsigned char* mbase = mask + (size_t)b * 1024 * 1024;
    float* abase = attn + bh * 1024 * 1024;

    __shared__ __align__(16) char PsRaw[32 * 2048];  // 64 KB unnormalized P (bf16)
    __shared__ bf16 Ks[2][64 * 32];                   // 8 KB [kh_d][key][d']
    __shared__ bf16 Vs[2][64 * 32];                   // 8 KB [kh_s][d][s']

    // staging: linear dest = tid*16 bytes per buffer half
    const int skey = tid >> 2;         // 0..63 (key for K, d for V)
    const int sch = (tid & 3) * 8;     // element offset of this thread's 16B

    // Q fragments (A-operand), persistent; issued first so they are oldest
    // in the vmcnt FIFO (compiler waits them before the first MFMA use).
    bf16x8 af[2];
    #pragma unroll
    for (int kh = 0; kh < 2; ++kh)
        af[kh] = *(const bf16x8*)(qbase + (size_t)(m0 + wq * 16 + c) * 64 + kh * 32 + quad * 8);

    // prologue: stage tile 0 (K pair, then V pair)
    gld_lds16(kbase + (size_t)skey * 64 + sch,       &Ks[0][skey * 32 + sch]);
    gld_lds16(kbase + (size_t)skey * 64 + 32 + sch,  &Ks[1][skey * 32 + sch]);
    gld_lds16(vbase + (size_t)skey * 1024 + sch,     &Vs[0][skey * 32 + sch]);
    gld_lds16(vbase + (size_t)skey * 1024 + 32 + sch, &Vs[1][skey * 32 + sch]);

    f32x4 acc2[2];
    acc2[0] = (f32x4){0.f, 0.f, 0.f, 0.f};
    acc2[1] = (f32x4){0.f, 0.f, 0.f, 0.f};
    float priv[4] = {0.f, 0.f, 0.f, 0.f};

    for (int t = 0; t < 16; ++t) {
        const int s0 = t * 64;

        // ---- bar1: K(t) ready (V(t) pair still outstanding) ----
        WAIT_VM2();
        SBAR();
        SFENCE();

        // ---- QK^T: S[q][key], q rows wq*16.., keys ws*32.. ----
        f32x4 sacc[2];
        sacc[0] = (f32x4){0.f, 0.f, 0.f, 0.f};
        sacc[1] = (f32x4){0.f, 0.f, 0.f, 0.f};
        #pragma unroll
        for (int nt = 0; nt < 2; ++nt)
            #pragma unroll
            for (int kh = 0; kh < 2; ++kh) {
                bf16x8 bv = *(const bf16x8*)&Ks[kh][(ws * 32 + nt * 16 + c) * 32 + quad * 8];
                sacc[nt] = MFMA16(af[kh], bv, sacc[nt]);
            }

        // ---- score -> exp -> P(LDS) + row-sum ----
        #pragma unroll
        for (int i = 0; i < 4; ++i) {
            const int row = wq * 16 + quad * 4 + i;
            const int q = m0 + row;
            const float* lrow = lps + (size_t)q * 1024 + s0 + ws * 32;
            const unsigned char* mrow = mbase + (size_t)q * 1024 + s0 + ws * 32;
            const int swz = (row & 7) << 4;
            #pragma unroll
            for (int nt = 0; nt < 2; ++nt) {
                const int col = s0 + ws * 32 + nt * 16 + c;
                float sc = sacc[nt][i] * 0.125f + cw * lrow[nt * 16 + c] + cbv;
                if (mrow[nt * 16 + c]) sc = -1e9f;
                float e = __expf(sc);
                priv[i] += e;
                *(bf16*)(PsRaw + row * 2048 + ((col * 2) ^ swz)) = (bf16)e;
            }
        }

        // ---- bar2: P visible to the ws pair, V(t) in LDS, Ks free ----
        WAIT_LGKM0();
        WAIT_VM0();
        SBAR();
        SFENCE();

        // issue K(t+1) (hides under PV + bar3, drained at next bar1's vmcnt(2))
        if (t < 15) {
            gld_lds16(kbase + (size_t)(s0 + 64 + skey) * 64 + sch,      &Ks[0][skey * 32 + sch]);
            gld_lds16(kbase + (size_t)(s0 + 64 + skey) * 64 + 32 + sch, &Ks[1][skey * 32 + sch]);
        }

        // ---- PV: ctx[q][d] += P[q][s] V[s][d], d half = ws ----
        const int prow = wq * 16 + c;
        const int pswz = (prow & 7) << 4;
        #pragma unroll
        for (int kh = 0; kh < 2; ++kh) {
            bf16x8 a2 = *(const bf16x8*)(PsRaw + prow * 2048 +
                                         (((s0 + kh * 32 + quad * 8) * 2) ^ pswz));
            #pragma unroll
            for (int nt = 0; nt < 2; ++nt) {
                bf16x8 b2v = *(const bf16x8*)&Vs[kh][(ws * 32 + nt * 16 + c) * 32 + quad * 8];
                acc2[nt] = MFMA16(a2, b2v, acc2[nt]);
            }
        }

        // ---- bar3: Vs free ----
        WAIT_LGKM0();
        SBAR();
        SFENCE();

        // issue V(t+1) (hides under next tile's bar1 + QK^T + exp)
        if (t < 15) {
            gld_lds16(vbase + (size_t)skey * 1024 + s0 + 64 + sch,      &Vs[0][skey * 32 + sch]);
            gld_lds16(vbase + (size_t)skey * 1024 + s0 + 64 + 32 + sch, &Vs[1][skey * 32 + sch]);
        }
    }

    // ---- row-sum combine across ws pair (Ks reused as scratch) ----
    float* rsp = (float*)&Ks[0][0];    // [2][32]
    float* rlz = rsp + 64;             // [32]
    #pragma unroll
    for (int i = 0; i < 4; ++i) {
        float v = priv[i];
        v += __shfl_xor(v, 1); v += __shfl_xor(v, 2);
        v += __shfl_xor(v, 4); v += __shfl_xor(v, 8);
        priv[i] = v;
    }
    if (c == 0) {
        #pragma unroll
        for (int i = 0; i < 4; ++i)
            rsp[ws * 32 + wq * 16 + quad * 4 + i] = priv[i];
    }
    __syncthreads();
    if (tid < 32) rlz[tid] = 1.0f / (rsp[tid] + rsp[32 + tid]);
    __syncthreads();

    // ---- ctx epilogue ----
    #pragma unroll
    for (int nt = 0; nt < 2; ++nt)
        #pragma unroll
        for (int i = 0; i < 4; ++i) {
            const int row = wq * 16 + quad * 4 + i;
            const int q = m0 + row;
            const int d = ws * 32 + nt * 16 + c;
            ctxb[((size_t)b * 1024 + q) * 1024 + h * 64 + d] = (bf16)(acc2[nt][i] * rlz[row]);
        }

    // ---- attn write: one q-row per pass, coalesced f32x4 ----
    for (int p = 0; p < 32; ++p) {
        const float rl = rlz[p];
        bf16x4 pv = *(const bf16x4*)(PsRaw + p * 2048 + ((tid * 8) ^ ((p & 7) << 4)));
        float4 o = {(float)pv[0] * rl, (float)pv[1] * rl,
                    (float)pv[2] * rl, (float)pv[3] * rl};
        *(float4*)(abase + (size_t)(m0 + p) * 1024 + tid * 4) = o;
    }
}

// ---------------------------------------------------------------------------
// Kernel 5: out_pre = ctx @ W_fc + input_Q, same m97 GEMM structure.
// ---------------------------------------------------------------------------
__global__ __launch_bounds__(256) void fc_gemm(
    const bf16* __restrict__ ctxb, const bf16* __restrict__ Wt,
    const float* __restrict__ resid, float* __restrict__ outp)
{
    const int n0 = blockIdx.x * 128;
    const int m0 = blockIdx.y * 128;
    const int tid = threadIdx.x, w = tid >> 6, lane = tid & 63;
    const int quad = lane >> 4, c = lane & 15;
    const int wm = w & 1, wn = w >> 1;

    __shared__ bf16 As[128 * 32];
    __shared__ bf16 Bs[128 * 32];

    f32x4 acc[4][4];
    #pragma unroll
    for (int mt = 0; mt < 4; ++mt)
        #pragma unroll
        for (int nt = 0; nt < 4; ++nt) acc[mt][nt] = (f32x4){0.f, 0.f, 0.f, 0.f};

    const int lrow = lane >> 2;
    const int lk = (lane & 3) * 8;

    for (int k0 = 0; k0 < 1024; k0 += 32) {
        #pragma unroll
        for (int half = 0; half < 2; ++half) {
            const int row = half * 64 + w * 16 + lrow;
            gld_lds16(ctxb + (size_t)(m0 + row) * 1024 + k0 + lk, As + row * 32 + lk);
            gld_lds16(Wt + (size_t)(n0 + row) * 1024 + k0 + lk, Bs + row * 32 + lk);
        }
        __syncthreads();
        bf16x8 af[4], bv[4];
        #pragma unroll
        for (int mt = 0; mt < 4; ++mt)
            af[mt] = *(const bf16x8*)&As[(wm * 64 + mt * 16 + c) * 32 + quad * 8];
        #pragma unroll
        for (int nt = 0; nt < 4; ++nt)
            bv[nt] = *(const bf16x8*)&Bs[(wn * 64 + nt * 16 + c) * 32 + quad * 8];
        #pragma unroll
        for (int mt = 0; mt < 4; ++mt)
            #pragma unroll
            for (int nt = 0; nt < 4; ++nt)
                acc[mt][nt] = MFMA16(af[mt], bv[nt], acc[mt][nt]);
        __syncthreads();
    }

    #pragma unroll
    for (int mt = 0; mt < 4; ++mt) {
        const int mb = m0 + wm * 64 + mt * 16 + quad * 4;
        #pragma unroll
        for (int nt = 0; nt < 4; ++nt) {
            const int n = n0 + wn * 64 + nt * 16 + c;
            #pragma unroll
            for (int i = 0; i < 4; ++i) {
                const size_t idx = (size_t)(mb + i) * 1024 + n;
                outp[idx] = acc[mt][nt][i] + resid[idx];
            }
        }
    }
}

// ---------------------------------------------------------------------------
// Kernel 6: LayerNorm over last dim (1024).
// ---------------------------------------------------------------------------
__global__ __launch_bounds__(256) void ln_kernel(
    const float* __restrict__ xp, float* __restrict__ out)
{
    const int row = blockIdx.x, tid = threadIdx.x;
    const float* p = xp + (size_t)row * 1024 + tid * 4;
    float4 x = *(const float4*)p;
    float s = x.x + x.y + x.z + x.w;
    float q = x.x * x.x + x.y * x.y + x.z * x.z + x.w * x.w;
    #pragma unroll
    for (int off = 32; off >= 1; off >>= 1) {
        s += __shfl_down(s, off);
        q += __shfl_down(q, off);
    }
    __shared__ float sb[4], qb[4];
    const int w = tid >> 6, lane = tid & 63;
    if (lane == 0) { sb[w] = s; qb[w] = q; }
    __syncthreads();
    const float ts = sb[0] + sb[1] + sb[2] + sb[3];
    const float tq = qb[0] + qb[1] + qb[2] + qb[3];
    const float mean = ts * (1.0f / 1024.0f);
    const float var = tq * (1.0f / 1024.0f) - mean * mean;
    const float rs = rsqrtf(var + 1e-5f);
    float4 o;
    o.x = (x.x - mean) * rs; o.y = (x.y - mean) * rs;
    o.z = (x.z - mean) * rs; o.w = (x.w - mean) * rs;
    *(float4*)(out + (size_t)row * 1024 + tid * 4) = o;
}

// ---------------------------------------------------------------------------
extern "C" void kernel_launch(void* const* d_in, const int* in_sizes, int n_in,
                              void* d_out, int out_size, void* d_ws, size_t ws_size,
                              hipStream_t stream)
{
    const float* Xq  = (const float*)d_in[0];
    const float* Xk  = (const float*)d_in[1];
    const float* Xv  = (const float*)d_in[2];
    const unsigned char* mask = (const unsigned char*)d_in[3];
    const float* lps = (const float*)d_in[4];
    const float* Wq  = (const float*)d_in[5];
    const float* Wk  = (const float*)d_in[6];
    const float* Wv  = (const float*)d_in[7];
    const float* Wfc = (const float*)d_in[8];
    const float* cw  = (const float*)d_in[9];
    const float* cb  = (const float*)d_in[10];

    char* ws = (char*)d_ws;
    const size_t MB = 1024 * 1024;
    bf16* Wtq = (bf16*)(ws + 0 * MB);
    bf16* Wtk = (bf16*)(ws + 2 * MB);
    bf16* Wtv = (bf16*)(ws + 4 * MB);
    bf16* Wtf = (bf16*)(ws + 6 * MB);
    bf16* Qb  = (bf16*)(ws + 8 * MB);      // [4][16][1024][64]
    bf16* Kb  = (bf16*)(ws + 16 * MB);     // [4][16][1024][64]
    bf16* VT  = (bf16*)(ws + 24 * MB);     // [4][16][64][1024]
    // Xbf lifetime: [xcast, qkv_gemm]; ctx written by attn (later), outp by fc
    bf16* Xbq = (bf16*)(ws + 32 * MB);     // overlaps ctx region
    bf16* Xbk = (bf16*)(ws + 40 * MB);     // overlaps outp region
    bf16* Xbv = (bf16*)(ws + 48 * MB);     // overlaps outp region
    bf16* ctx = (bf16*)(ws + 32 * MB);     // [4096][1024] bf16
    float* outp = (float*)(ws + 40 * MB);  // [4096][1024] f32

    float* out_ln = (float*)d_out;
    float* attn   = (float*)d_out + (size_t)4 * MB;

    wcvt_kernel<<<dim3(16, 16, 4), 256, 0, stream>>>(Wq, Wk, Wv, Wfc, Wtq, Wtk, Wtv, Wtf);
    xcast_kernel<<<dim3(2048, 1, 3), 256, 0, stream>>>(Xq, Xk, Xv, Xbq, Xbk, Xbv);
    qkv_gemm<<<dim3(8, 32, 3), 256, 0, stream>>>(Xbq, Xbk, Xbv, Wtq, Wtk, Wtv, Qb, Kb, VT);
    attn_kernel<<<dim3(32, 16, 4), 256, 0, stream>>>(Qb, Kb, VT, lps, mask, cw, cb, attn, ctx);
    fc_gemm<<<dim3(8, 32, 1), 256, 0, stream>>>(ctx, Wtf, Xq, outp);
    ln_kernel<<<4096, 256, 0, stream>>>(outp, out_ln);
}

// Round 6
// 502.719 us; speedup vs baseline: 1.5163x; 1.1237x over previous
//
#include <hip/hip_runtime.h>
#include <hip/hip_bf16.h>

typedef __bf16 bf16;
typedef __attribute__((ext_vector_type(8))) __bf16 bf16x8;
typedef __attribute__((ext_vector_type(4))) __bf16 bf16x4;
typedef __attribute__((ext_vector_type(4))) float f32x4;

#define MFMA16(a, b, c) __builtin_amdgcn_mfma_f32_16x16x32_bf16((a), (b), (c), 0, 0, 0)

__device__ __forceinline__ void gld_lds16(const bf16* g, bf16* l) {
    __builtin_amdgcn_global_load_lds(
        (const __attribute__((address_space(1))) void*)g,
        (__attribute__((address_space(3))) void*)l, 16, 0, 0);
}

#define WAIT_VM2()   asm volatile("s_waitcnt vmcnt(2)" ::: "memory")
#define WAIT_VM0()   asm volatile("s_waitcnt vmcnt(0)" ::: "memory")
#define WAIT_LGKM0() asm volatile("s_waitcnt lgkmcnt(0)" ::: "memory")
#define SBAR()       __builtin_amdgcn_s_barrier()
#define SFENCE()     __builtin_amdgcn_sched_barrier(0)

// ---------------------------------------------------------------------------
// Kernel 1: weight transpose + f32->bf16 cast.  W [1024(k)][1024(n)] f32 ->
// Wt [1024(n)][1024(k)] bf16.
// ---------------------------------------------------------------------------
__global__ __launch_bounds__(256) void wcvt_kernel(
    const float* __restrict__ W0, const float* __restrict__ W1,
    const float* __restrict__ W2, const float* __restrict__ W3,
    bf16* __restrict__ T0, bf16* __restrict__ T1,
    bf16* __restrict__ T2, bf16* __restrict__ T3)
{
    const int z = blockIdx.z;
    const float* W = (z == 0) ? W0 : (z == 1) ? W1 : (z == 2) ? W2 : W3;
    bf16* T = (z == 0) ? T0 : (z == 1) ? T1 : (z == 2) ? T2 : T3;
    const int k0 = blockIdx.x * 64, n0 = blockIdx.y * 64;
    const int tid = threadIdx.x;

    __shared__ float tile[64][65];

    #pragma unroll
    for (int rr = 0; rr < 4; ++rr) {
        int r = (tid >> 4) + rr * 16;
        int cg = (tid & 15) * 4;
        float4 v = *(const float4*)(W + (size_t)(k0 + r) * 1024 + n0 + cg);
        tile[r][cg + 0] = v.x; tile[r][cg + 1] = v.y;
        tile[r][cg + 2] = v.z; tile[r][cg + 3] = v.w;
    }
    __syncthreads();

    const int n_local = tid >> 2;
    const int kg = (tid & 3) * 16;
    bf16x8 v0, v1;
    #pragma unroll
    for (int j = 0; j < 8; ++j) v0[j] = (bf16)tile[kg + j][n_local];
    #pragma unroll
    for (int j = 0; j < 8; ++j) v1[j] = (bf16)tile[kg + 8 + j][n_local];
    bf16* dst = T + (size_t)(n0 + n_local) * 1024 + k0 + kg;
    *(bf16x8*)dst = v0;
    *(bf16x8*)(dst + 8) = v1;
}

// ---------------------------------------------------------------------------
// Kernel 2: X f32 -> bf16 cast (enables global_load_lds staging in the GEMM).
// ---------------------------------------------------------------------------
__global__ __launch_bounds__(256) void xcast_kernel(
    const float* __restrict__ Xq, const float* __restrict__ Xk, const float* __restrict__ Xv,
    bf16* __restrict__ Yq, bf16* __restrict__ Yk, bf16* __restrict__ Yv)
{
    const int z = blockIdx.z;
    const float* X = (z == 0) ? Xq : (z == 1) ? Xk : Xv;
    bf16* Y = (z == 0) ? Yq : (z == 1) ? Yk : Yv;
    const size_t i = ((size_t)blockIdx.x * 256 + threadIdx.x) * 8;
    float4 a = *(const float4*)(X + i);
    float4 b = *(const float4*)(X + i + 4);
    bf16x8 o = {(bf16)a.x, (bf16)a.y, (bf16)a.z, (bf16)a.w,
                (bf16)b.x, (bf16)b.y, (bf16)b.z, (bf16)b.w};
    *(bf16x8*)(Y + i) = o;
}

// ---------------------------------------------------------------------------
// Kernel 3: QKV projection, m97-style. 128x128 tile, 4 waves (each 64x64),
// LDS staging via global_load_lds width=16, K-step 32.
// Epilogue bounces C through LDS so ALL global stores are bf16x8 coalesced
// (previously: Q/K = 64x 2B scatter stores/thread at 32B-segment granularity,
// VT = 16x 8B stores to rows 2KB apart -- memory-pipe amplification on 2/3+
// of launches).
// ---------------------------------------------------------------------------
__global__ __launch_bounds__(256) void qkv_gemm(
    const bf16* __restrict__ Xq, const bf16* __restrict__ Xk, const bf16* __restrict__ Xv,
    const bf16* __restrict__ Wtq, const bf16* __restrict__ Wtk, const bf16* __restrict__ Wtv,
    bf16* __restrict__ Qb, bf16* __restrict__ Kb, bf16* __restrict__ VT)
{
    const int z = blockIdx.z;
    const bf16* X = (z == 0) ? Xq : (z == 1) ? Xk : Xv;
    const bf16* Wt = (z == 0) ? Wtq : (z == 1) ? Wtk : Wtv;
    const int n0 = blockIdx.x * 128;
    const int m0 = blockIdx.y * 128;
    const int tid = threadIdx.x, w = tid >> 6, lane = tid & 63;
    const int quad = lane >> 4, c = lane & 15;
    const int wm = w & 1, wn = w >> 1;

    // staging (2x 8KB) and epilogue bounce (18KB) share one allocation
    __shared__ __align__(16) bf16 SH[9216];
    bf16* As = SH;
    bf16* Bs = SH + 4096;

    f32x4 acc[4][4];
    #pragma unroll
    for (int mt = 0; mt < 4; ++mt)
        #pragma unroll
        for (int nt = 0; nt < 4; ++nt) acc[mt][nt] = (f32x4){0.f, 0.f, 0.f, 0.f};

    const int lrow = lane >> 2;        // 0..15
    const int lk = (lane & 3) * 8;     // 0,8,16,24

    for (int k0 = 0; k0 < 1024; k0 += 32) {
        #pragma unroll
        for (int half = 0; half < 2; ++half) {
            const int row = half * 64 + w * 16 + lrow;
            gld_lds16(X + (size_t)(m0 + row) * 1024 + k0 + lk, As + row * 32 + lk);
            gld_lds16(Wt + (size_t)(n0 + row) * 1024 + k0 + lk, Bs + row * 32 + lk);
        }
        __syncthreads();
        bf16x8 af[4], bv[4];
        #pragma unroll
        for (int mt = 0; mt < 4; ++mt)
            af[mt] = *(const bf16x8*)&As[(wm * 64 + mt * 16 + c) * 32 + quad * 8];
        #pragma unroll
        for (int nt = 0; nt < 4; ++nt)
            bv[nt] = *(const bf16x8*)&Bs[(wn * 64 + nt * 16 + c) * 32 + quad * 8];
        #pragma unroll
        for (int mt = 0; mt < 4; ++mt)
            #pragma unroll
            for (int nt = 0; nt < 4; ++nt)
                acc[mt][nt] = MFMA16(af[mt], bv[nt], acc[mt][nt]);
        __syncthreads();
    }

    const int b = m0 >> 10;            // batch (m0 % 128 == 0, 128 | 1024)
    const int sbase = m0 & 1023;       // s within batch

    if (z == 2) {
        // VT [bh*64+d][1024 s]; per head-half: SH[64 d][136 stride, 128 s]
        #pragma unroll
        for (int nh = 0; nh < 2; ++nh) {
            if (wn == nh) {
                #pragma unroll
                for (int mt = 0; mt < 4; ++mt)
                    #pragma unroll
                    for (int nt = 0; nt < 4; ++nt) {
                        bf16x4 v = {(bf16)acc[mt][nt][0], (bf16)acc[mt][nt][1],
                                    (bf16)acc[mt][nt][2], (bf16)acc[mt][nt][3]};
                        *(bf16x4*)&SH[(nt * 16 + c) * 136 + wm * 64 + mt * 16 + quad * 4] = v;
                    }
            }
            __syncthreads();
            const int h = (n0 >> 6) + nh;
            #pragma unroll
            for (int p = 0; p < 4; ++p) {
                const int d = p * 16 + (tid >> 4);
                const int sg = (tid & 15) * 8;
                bf16x8 v = *(const bf16x8*)&SH[d * 136 + sg];
                *(bf16x8*)(VT + ((size_t)(b * 16 + h) * 64 + d) * 1024 + sbase + sg) = v;
            }
            __syncthreads();
        }
    } else {
        // Q/K [bh][s][64 d]; per head-half: SH[128 s][72 stride, 64 d]
        bf16* Ob = (z == 0) ? Qb : Kb;
        #pragma unroll
        for (int nh = 0; nh < 2; ++nh) {
            if (wn == nh) {
                #pragma unroll
                for (int mt = 0; mt < 4; ++mt)
                    #pragma unroll
                    for (int nt = 0; nt < 4; ++nt)
                        #pragma unroll
                        for (int i = 0; i < 4; ++i)
                            SH[(wm * 64 + mt * 16 + quad * 4 + i) * 72 + nt * 16 + c] =
                                (bf16)acc[mt][nt][i];
            }
            __syncthreads();
            const int h = (n0 >> 6) + nh;
            bf16* dstb = Ob + (size_t)(b * 16 + h) * 1024 * 64;
            #pragma unroll
            for (int p = 0; p < 4; ++p) {
                const int r = p * 32 + (tid >> 3);
                const int cg = (tid & 7) * 8;
                bf16x8 v = *(const bf16x8*)&SH[r * 72 + cg];
                *(bf16x8*)(dstb + (size_t)(sbase + r) * 64 + cg) = v;
            }
            __syncthreads();
        }
    }
}

// ---------------------------------------------------------------------------
// Kernel 4: single-sweep deferred-normalization attention, counted-vmcnt
// pipeline (as Round 4) + REGISTER PREFETCH of lps/mask one full tile ahead.
// lps/mask(t+1) are issued right after bar2's vmcnt(0), BEFORE the K(t+1)
// pair, so at bar1 the youngest two VMEM loads are always the V pair ->
// vmcnt(2) semantics unchanged (and safe under any compiler reordering:
// K always has >=2 younger loads).  Their latency is now covered by a full
// tile (~PV+bar+QK) instead of being exposed inside the exp phase.
// ---------------------------------------------------------------------------
__global__ __launch_bounds__(256) void attn_kernel(
    const bf16* __restrict__ Qb, const bf16* __restrict__ Kb, const bf16* __restrict__ VT,
    const float* __restrict__ lps, const unsigned char* __restrict__ mask,
    const float* __restrict__ cwp, const float* __restrict__ cbp,
    float* __restrict__ attn, bf16* __restrict__ ctxb)
{
    const int qt = blockIdx.x, h = blockIdx.y, b = blockIdx.z;
    const int tid = threadIdx.x, w = tid >> 6, lane = tid & 63;
    const int quad = lane >> 4, c = lane & 15;
    const int wq = w & 1, ws = w >> 1;
    const float cw = cwp[0], cbv = cbp[0];
    const int m0 = qt * 32;
    const size_t bh = (size_t)(b * 16 + h);

    const bf16* qbase = Qb + bh * 1024 * 64;
    const bf16* kbase = Kb + bh * 1024 * 64;
    const bf16* vbase = VT + bh * 64 * 1024;
    float* abase = attn + bh * 1024 * 1024;

    // per-thread base pointers for bias/mask rows (row i at +i*1024)
    const float* lp0 = lps + (size_t)(m0 + wq * 16 + quad * 4) * 1024 + ws * 32 + c;
    const unsigned char* mp0 = mask + (size_t)b * 1024 * 1024 +
                               (size_t)(m0 + wq * 16 + quad * 4) * 1024 + ws * 32 + c;

    __shared__ __align__(16) char PsRaw[32 * 2048];  // 64 KB unnormalized P (bf16)
    __shared__ bf16 Ks[2][64 * 32];                   // 8 KB [kh_d][key][d']
    __shared__ bf16 Vs[2][64 * 32];                   // 8 KB [kh_s][d][s']

    const int skey = tid >> 2;         // 0..63 (key for K, d for V)
    const int sch = (tid & 3) * 8;     // element offset of this thread's 16B

    // Q fragments (A-operand), persistent
    bf16x8 af[2];
    #pragma unroll
    for (int kh = 0; kh < 2; ++kh)
        af[kh] = *(const bf16x8*)(qbase + (size_t)(m0 + wq * 16 + c) * 64 + kh * 32 + quad * 8);

    // prologue: K pair, lps/mask(0) into regs, V pair LAST (vmcnt anchor)
    gld_lds16(kbase + (size_t)skey * 64 + sch,       &Ks[0][skey * 32 + sch]);
    gld_lds16(kbase + (size_t)skey * 64 + 32 + sch,  &Ks[1][skey * 32 + sch]);
    float lpv[4][2];
    unsigned char mkv[4][2];
    #pragma unroll
    for (int i = 0; i < 4; ++i)
        #pragma unroll
        for (int nt = 0; nt < 2; ++nt) {
            lpv[i][nt] = lp0[(size_t)i * 1024 + nt * 16];
            mkv[i][nt] = mp0[(size_t)i * 1024 + nt * 16];
        }
    gld_lds16(vbase + (size_t)skey * 1024 + sch,      &Vs[0][skey * 32 + sch]);
    gld_lds16(vbase + (size_t)skey * 1024 + 32 + sch, &Vs[1][skey * 32 + sch]);

    f32x4 acc2[2];
    acc2[0] = (f32x4){0.f, 0.f, 0.f, 0.f};
    acc2[1] = (f32x4){0.f, 0.f, 0.f, 0.f};
    float priv[4] = {0.f, 0.f, 0.f, 0.f};

    for (int t = 0; t < 16; ++t) {
        const int s0 = t * 64;

        // ---- bar1: K(t) ready (V(t) pair still outstanding) ----
        WAIT_VM2();
        SBAR();
        SFENCE();

        // ---- QK^T ----
        f32x4 sacc[2];
        sacc[0] = (f32x4){0.f, 0.f, 0.f, 0.f};
        sacc[1] = (f32x4){0.f, 0.f, 0.f, 0.f};
        #pragma unroll
        for (int nt = 0; nt < 2; ++nt)
            #pragma unroll
            for (int kh = 0; kh < 2; ++kh) {
                bf16x8 bv = *(const bf16x8*)&Ks[kh][(ws * 32 + nt * 16 + c) * 32 + quad * 8];
                sacc[nt] = MFMA16(af[kh], bv, sacc[nt]);
            }

        // ---- score -> exp -> P(LDS) + row-sum (bias/mask from regs) ----
        #pragma unroll
        for (int i = 0; i < 4; ++i) {
            const int row = wq * 16 + quad * 4 + i;
            const int swz = (row & 7) << 4;
            #pragma unroll
            for (int nt = 0; nt < 2; ++nt) {
                const int col = s0 + ws * 32 + nt * 16 + c;
                float sc = sacc[nt][i] * 0.125f + cw * lpv[i][nt] + cbv;
                if (mkv[i][nt]) sc = -1e9f;
                float e = __expf(sc);
                priv[i] += e;
                *(bf16*)(PsRaw + row * 2048 + ((col * 2) ^ swz)) = (bf16)e;
            }
        }

        // ---- bar2: P visible, V(t) in LDS, Ks free ----
        WAIT_LGKM0();
        WAIT_VM0();
        SBAR();
        SFENCE();

        // prefetch lps/mask(t+1) into regs, then K(t+1) (V stays youngest)
        float lpn[4][2];
        unsigned char mkn[4][2];
        if (t < 15) {
            #pragma unroll
            for (int i = 0; i < 4; ++i)
                #pragma unroll
                for (int nt = 0; nt < 2; ++nt) {
                    lpn[i][nt] = lp0[(size_t)i * 1024 + s0 + 64 + nt * 16];
                    mkn[i][nt] = mp0[(size_t)i * 1024 + s0 + 64 + nt * 16];
                }
            gld_lds16(kbase + (size_t)(s0 + 64 + skey) * 64 + sch,      &Ks[0][skey * 32 + sch]);
            gld_lds16(kbase + (size_t)(s0 + 64 + skey) * 64 + 32 + sch, &Ks[1][skey * 32 + sch]);
        }
        SFENCE();

        // ---- PV ----
        const int prow = wq * 16 + c;
        const int pswz = (prow & 7) << 4;
        #pragma unroll
        for (int kh = 0; kh < 2; ++kh) {
            bf16x8 a2 = *(const bf16x8*)(PsRaw + prow * 2048 +
                                         (((s0 + kh * 32 + quad * 8) * 2) ^ pswz));
            #pragma unroll
            for (int nt = 0; nt < 2; ++nt) {
                bf16x8 b2v = *(const bf16x8*)&Vs[kh][(ws * 32 + nt * 16 + c) * 32 + quad * 8];
                acc2[nt] = MFMA16(a2, b2v, acc2[nt]);
            }
        }

        // ---- bar3: Vs free ----
        WAIT_LGKM0();
        SBAR();
        SFENCE();

        // issue V(t+1); rotate bias/mask regs
        if (t < 15) {
            gld_lds16(vbase + (size_t)skey * 1024 + s0 + 64 + sch,      &Vs[0][skey * 32 + sch]);
            gld_lds16(vbase + (size_t)skey * 1024 + s0 + 64 + 32 + sch, &Vs[1][skey * 32 + sch]);
            #pragma unroll
            for (int i = 0; i < 4; ++i)
                #pragma unroll
                for (int nt = 0; nt < 2; ++nt) {
                    lpv[i][nt] = lpn[i][nt];
                    mkv[i][nt] = mkn[i][nt];
                }
        }
    }

    // ---- row-sum combine across ws pair (Ks reused as scratch) ----
    float* rsp = (float*)&Ks[0][0];    // [2][32]
    float* rlz = rsp + 64;             // [32]
    #pragma unroll
    for (int i = 0; i < 4; ++i) {
        float v = priv[i];
        v += __shfl_xor(v, 1); v += __shfl_xor(v, 2);
        v += __shfl_xor(v, 4); v += __shfl_xor(v, 8);
        priv[i] = v;
    }
    if (c == 0) {
        #pragma unroll
        for (int i = 0; i < 4; ++i)
            rsp[ws * 32 + wq * 16 + quad * 4 + i] = priv[i];
    }
    __syncthreads();
    if (tid < 32) rlz[tid] = 1.0f / (rsp[tid] + rsp[32 + tid]);
    __syncthreads();

    // ---- ctx epilogue ----
    #pragma unroll
    for (int nt = 0; nt < 2; ++nt)
        #pragma unroll
        for (int i = 0; i < 4; ++i) {
            const int row = wq * 16 + quad * 4 + i;
            const int q = m0 + row;
            const int d = ws * 32 + nt * 16 + c;
            ctxb[((size_t)b * 1024 + q) * 1024 + h * 64 + d] = (bf16)(acc2[nt][i] * rlz[row]);
        }

    // ---- attn write: one q-row per pass, coalesced f32x4 ----
    for (int p = 0; p < 32; ++p) {
        const float rl = rlz[p];
        bf16x4 pv = *(const bf16x4*)(PsRaw + p * 2048 + ((tid * 8) ^ ((p & 7) << 4)));
        float4 o = {(float)pv[0] * rl, (float)pv[1] * rl,
                    (float)pv[2] * rl, (float)pv[3] * rl};
        *(float4*)(abase + (size_t)(m0 + p) * 1024 + tid * 4) = o;
    }
}

// ---------------------------------------------------------------------------
// Kernel 5: out_pre = ctx @ W_fc + input_Q, same m97 GEMM structure.
// ---------------------------------------------------------------------------
__global__ __launch_bounds__(256) void fc_gemm(
    const bf16* __restrict__ ctxb, const bf16* __restrict__ Wt,
    const float* __restrict__ resid, float* __restrict__ outp)
{
    const int n0 = blockIdx.x * 128;
    const int m0 = blockIdx.y * 128;
    const int tid = threadIdx.x, w = tid >> 6, lane = tid & 63;
    const int quad = lane >> 4, c = lane & 15;
    const int wm = w & 1, wn = w >> 1;

    __shared__ bf16 As[128 * 32];
    __shared__ bf16 Bs[128 * 32];

    f32x4 acc[4][4];
    #pragma unroll
    for (int mt = 0; mt < 4; ++mt)
        #pragma unroll
        for (int nt = 0; nt < 4; ++nt) acc[mt][nt] = (f32x4){0.f, 0.f, 0.f, 0.f};

    const int lrow = lane >> 2;
    const int lk = (lane & 3) * 8;

    for (int k0 = 0; k0 < 1024; k0 += 32) {
        #pragma unroll
        for (int half = 0; half < 2; ++half) {
            const int row = half * 64 + w * 16 + lrow;
            gld_lds16(ctxb + (size_t)(m0 + row) * 1024 + k0 + lk, As + row * 32 + lk);
            gld_lds16(Wt + (size_t)(n0 + row) * 1024 + k0 + lk, Bs + row * 32 + lk);
        }
        __syncthreads();
        bf16x8 af[4], bv[4];
        #pragma unroll
        for (int mt = 0; mt < 4; ++mt)
            af[mt] = *(const bf16x8*)&As[(wm * 64 + mt * 16 + c) * 32 + quad * 8];
        #pragma unroll
        for (int nt = 0; nt < 4; ++nt)
            bv[nt] = *(const bf16x8*)&Bs[(wn * 64 + nt * 16 + c) * 32 + quad * 8];
        #pragma unroll
        for (int mt = 0; mt < 4; ++mt)
            #pragma unroll
            for (int nt = 0; nt < 4; ++nt)
                acc[mt][nt] = MFMA16(af[mt], bv[nt], acc[mt][nt]);
        __syncthreads();
    }

    #pragma unroll
    for (int mt = 0; mt < 4; ++mt) {
        const int mb = m0 + wm * 64 + mt * 16 + quad * 4;
        #pragma unroll
        for (int nt = 0; nt < 4; ++nt) {
            const int n = n0 + wn * 64 + nt * 16 + c;
            #pragma unroll
            for (int i = 0; i < 4; ++i) {
                const size_t idx = (size_t)(mb + i) * 1024 + n;
                outp[idx] = acc[mt][nt][i] + resid[idx];
            }
        }
    }
}

// ---------------------------------------------------------------------------
// Kernel 6: LayerNorm over last dim (1024).
// ---------------------------------------------------------------------------
__global__ __launch_bounds__(256) void ln_kernel(
    const float* __restrict__ xp, float* __restrict__ out)
{
    const int row = blockIdx.x, tid = threadIdx.x;
    const float* p = xp + (size_t)row * 1024 + tid * 4;
    float4 x = *(const float4*)p;
    float s = x.x + x.y + x.z + x.w;
    float q = x.x * x.x + x.y * x.y + x.z * x.z + x.w * x.w;
    #pragma unroll
    for (int off = 32; off >= 1; off >>= 1) {
        s += __shfl_down(s, off);
        q += __shfl_down(q, off);
    }
    __shared__ float sb[4], qb[4];
    const int w = tid >> 6, lane = tid & 63;
    if (lane == 0) { sb[w] = s; qb[w] = q; }
    __syncthreads();
    const float ts = sb[0] + sb[1] + sb[2] + sb[3];
    const float tq = qb[0] + qb[1] + qb[2] + qb[3];
    const float mean = ts * (1.0f / 1024.0f);
    const float var = tq * (1.0f / 1024.0f) - mean * mean;
    const float rs = rsqrtf(var + 1e-5f);
    float4 o;
    o.x = (x.x - mean) * rs; o.y = (x.y - mean) * rs;
    o.z = (x.z - mean) * rs; o.w = (x.w - mean) * rs;
    *(float4*)(out + (size_t)row * 1024 + tid * 4) = o;
}

// ---------------------------------------------------------------------------
extern "C" void kernel_launch(void* const* d_in, const int* in_sizes, int n_in,
                              void* d_out, int out_size, void* d_ws, size_t ws_size,
                              hipStream_t stream)
{
    const float* Xq  = (const float*)d_in[0];
    const float* Xk  = (const float*)d_in[1];
    const float* Xv  = (const float*)d_in[2];
    const unsigned char* mask = (const unsigned char*)d_in[3];
    const float* lps = (const float*)d_in[4];
    const float* Wq  = (const float*)d_in[5];
    const float* Wk  = (const float*)d_in[6];
    const float* Wv  = (const float*)d_in[7];
    const float* Wfc = (const float*)d_in[8];
    const float* cw  = (const float*)d_in[9];
    const float* cb  = (const float*)d_in[10];

    char* ws = (char*)d_ws;
    const size_t MB = 1024 * 1024;
    bf16* Wtq = (bf16*)(ws + 0 * MB);
    bf16* Wtk = (bf16*)(ws + 2 * MB);
    bf16* Wtv = (bf16*)(ws + 4 * MB);
    bf16* Wtf = (bf16*)(ws + 6 * MB);
    bf16* Qb  = (bf16*)(ws + 8 * MB);      // [4][16][1024][64]
    bf16* Kb  = (bf16*)(ws + 16 * MB);     // [4][16][1024][64]
    bf16* VT  = (bf16*)(ws + 24 * MB);     // [4][16][64][1024]
    // Xbf lifetime: [xcast, qkv_gemm]; ctx written by attn (later), outp by fc
    bf16* Xbq = (bf16*)(ws + 32 * MB);     // overlaps ctx region
    bf16* Xbk = (bf16*)(ws + 40 * MB);     // overlaps outp region
    bf16* Xbv = (bf16*)(ws + 48 * MB);     // overlaps outp region
    bf16* ctx = (bf16*)(ws + 32 * MB);     // [4096][1024] bf16
    float* outp = (float*)(ws + 40 * MB);  // [4096][1024] f32

    float* out_ln = (float*)d_out;
    float* attn   = (float*)d_out + (size_t)4 * MB;

    wcvt_kernel<<<dim3(16, 16, 4), 256, 0, stream>>>(Wq, Wk, Wv, Wfc, Wtq, Wtk, Wtv, Wtf);
    xcast_kernel<<<dim3(2048, 1, 3), 256, 0, stream>>>(Xq, Xk, Xv, Xbq, Xbk, Xbv);
    qkv_gemm<<<dim3(8, 32, 3), 256, 0, stream>>>(Xbq, Xbk, Xbv, Wtq, Wtk, Wtv, Qb, Kb, VT);
    attn_kernel<<<dim3(32, 16, 4), 256, 0, stream>>>(Qb, Kb, VT, lps, mask, cw, cb, attn, ctx);
    fc_gemm<<<dim3(8, 32, 1), 256, 0, stream>>>(ctx, Wtf, Xq, outp);
    ln_kernel<<<4096, 256, 0, stream>>>(outp, out_ln);
}